// Round 1
// 1178.571 us; speedup vs baseline: 1.0398x; 1.0398x over previous
//
#include <hip/hip_runtime.h>
#include <cstdint>
#include <cstddef>

// ---------------------------------------------------------------- types
typedef __bf16 bf16_t;
typedef __bf16 bf16x8 __attribute__((ext_vector_type(8)));
typedef __bf16 bf16x4 __attribute__((ext_vector_type(4)));
typedef float  f32x4  __attribute__((ext_vector_type(4)));

#define DEV __device__ __forceinline__

static constexpr int   BATCH = 2;
static constexpr int   NTOK  = 1024;
static constexpr int   DIM   = 1024;
static constexpr int   MROWS = BATCH * NTOK;      // 2048 token rows
static constexpr float SCALE = 0.125f;            // 64^-0.5

// ------------------------------------------------------- global->LDS DMA
DEV void load_lds16(const bf16_t* g, bf16_t* s) {
  __builtin_amdgcn_global_load_lds(
      (const __attribute__((address_space(1))) void*)g,
      (__attribute__((address_space(3))) void*)s, 16, 0, 0);
}

// ------------------------------------------------------------ reductions
DEV float wave_sum(float v) {
#pragma unroll
  for (int m = 1; m < 64; m <<= 1) v += __shfl_xor(v, m, 64);
  return v;
}
DEV float block_sum(float v, float* sb) {
  v = wave_sum(v);
  __syncthreads();
  if ((threadIdx.x & 63) == 0) sb[threadIdx.x >> 6] = v;
  __syncthreads();
  return sb[0] + sb[1] + sb[2] + sb[3];
}

// ------------------------------------------------------------------ GEMM
// C[M,N] = A[M,K] @ B[K,N], with B given transposed: BT[N][K] (row-major).
// Fragment layout (verified):
//   A frag:  A[m = lane&15][k = (lane>>4)*8 + j]   -> 8 contiguous bf16
//   B frag:  BT[n = lane&15][k = (lane>>4)*8 + j]  -> 8 contiguous bf16
//   C/D:     col = lane&15, row = (lane>>4)*4 + reg
// MODE 0: C(bf16) = alpha * acc
// MODE 1: C(bf16) = acc + bias[col]
// MODE 2: C(f32) += (acc + bias[col]) * ls[col]   (residual update in place)
// MODE 3: GEGLU epilogue. B rows are permuted a/g 16-col interleave; frag
//         pair (2p, 2p+1) = (a, g) for the SAME output col in the SAME lane.
//         C(bf16)[row][cf] = (a+ba) * gelu(g+bg), ldc = N/2.
// MODE 4: QKV epilogue. cols < 2048 (Q,K) -> C as bf16; cols >= 2048 (V)
//         -> vtp[z=b*16+h][d][tok] transposed store (feeds flash_attn).
template <int BM, int BN, int WR, int WC, int MODE>
__global__ __launch_bounds__(256) void gemm_bt(
    const bf16_t* __restrict__ A, long sA0, long sA1, int lda,
    const bf16_t* __restrict__ B, long sB0, long sB1, int ldb,
    void* __restrict__ Cv, long sC0, long sC1, int ldc,
    int K, float alpha, const float* __restrict__ bias,
    const float* __restrict__ ls, bf16_t* __restrict__ vtp) {
  constexpr int TM = BM / WR / 16;
  constexpr int TN = BN / WC / 16;
  __shared__ __attribute__((aligned(16))) bf16_t As[BM * 32];
  __shared__ __attribute__((aligned(16))) bf16_t Bs[BN * 32];

  const int tid  = threadIdx.x;
  const int lane = tid & 63, wave = tid >> 6;
  const int z  = blockIdx.z;
  const int zh = z >> 4, zl = z & 15;
  A += (size_t)zh * sA0 + (size_t)zl * sA1;
  B += (size_t)zh * sB0 + (size_t)zl * sB1;

  const int m0 = blockIdx.y * BM, n0 = blockIdx.x * BN;
  const int wm = (wave / WC) * (BM / WR);
  const int wn = (wave % WC) * (BN / WC);
  const int fm = lane & 15, quad = lane >> 4;

  f32x4 acc[TM][TN] = {};

  for (int k0 = 0; k0 < K; k0 += 32) {
#pragma unroll
    for (int c = tid; c < BM * 4; c += 256) {
      const int row = c >> 2, kc = (c & 3) << 3;
      load_lds16(A + (size_t)(m0 + row) * lda + k0 + kc, &As[c * 8]);
    }
#pragma unroll
    for (int c = tid; c < BN * 4; c += 256) {
      const int row = c >> 2, kc = (c & 3) << 3;
      load_lds16(B + (size_t)(n0 + row) * ldb + k0 + kc, &Bs[c * 8]);
    }
    __syncthreads();

    bf16x8 af[TM], bfr[TN];
#pragma unroll
    for (int i = 0; i < TM; ++i)
      af[i] = *(const bf16x8*)&As[(wm + i * 16 + fm) * 32 + quad * 8];
#pragma unroll
    for (int j = 0; j < TN; ++j)
      bfr[j] = *(const bf16x8*)&Bs[(wn + j * 16 + fm) * 32 + quad * 8];
#pragma unroll
    for (int i = 0; i < TM; ++i)
#pragma unroll
      for (int j = 0; j < TN; ++j)
        acc[i][j] = __builtin_amdgcn_mfma_f32_16x16x32_bf16(af[i], bfr[j],
                                                            acc[i][j], 0, 0, 0);
    __syncthreads();
  }

  const size_t coff = (size_t)zh * sC0 + (size_t)zl * sC1;
  if constexpr (MODE == 3) {
    // GEGLU: frag pairs (a = acc[i][2p], g = acc[i][2p+1]) -> ff col cf
    bf16_t* C = (bf16_t*)Cv;
#pragma unroll
    for (int i = 0; i < TM; ++i) {
      const int rowb = m0 + wm + i * 16 + quad * 4;
#pragma unroll
      for (int p = 0; p < TN / 2; ++p) {
        const int   cf = ((n0 + wn) >> 1) + p * 16 + fm;  // 0..4095
        const float ba = bias[cf], bg = bias[4096 + cf];
#pragma unroll
        for (int r = 0; r < 4; ++r) {
          const float a  = acc[i][2 * p][r] + ba;
          const float g  = acc[i][2 * p + 1][r] + bg;
          const float ge = 0.5f * g * (1.f + erff(g * 0.70710678118654752f));
          C[(size_t)(rowb + r) * ldc + cf] = (bf16_t)(a * ge);
        }
      }
    }
  } else if constexpr (MODE == 4) {
    bf16_t* C = (bf16_t*)Cv;
#pragma unroll
    for (int i = 0; i < TM; ++i) {
#pragma unroll
      for (int j = 0; j < TN; ++j) {
        const int col  = n0 + wn + j * 16 + fm;
        const int rowb = m0 + wm + i * 16 + quad * 4;
        if (col < 2048) {  // Q,K region: normal bf16 store
#pragma unroll
          for (int r = 0; r < 4; ++r)
            C[(size_t)(rowb + r) * ldc + col] = (bf16_t)acc[i][j][r];
        } else {           // V region: transposed store into vT[z][d][tok]
          const int hh = (col - 2048) >> 6, d = (col - 2048) & 63;
#pragma unroll
          for (int r = 0; r < 4; ++r) {
            const int row = rowb + r, bb = row >> 10, tok = row & 1023;
            vtp[((size_t)(bb * 16 + hh) * 64 + d) * 1024 + tok] =
                (bf16_t)acc[i][j][r];
          }
        }
      }
    }
  } else {
#pragma unroll
    for (int i = 0; i < TM; ++i) {
#pragma unroll
      for (int j = 0; j < TN; ++j) {
        const int col  = n0 + wn + j * 16 + fm;
        const int rowb = m0 + wm + i * 16 + quad * 4;
#pragma unroll
        for (int r = 0; r < 4; ++r) {
          const float  v   = acc[i][j][r];
          const size_t idx = coff + (size_t)(rowb + r) * ldc + col;
          if constexpr (MODE == 0) {
            ((bf16_t*)Cv)[idx] = (bf16_t)(v * alpha);
          } else if constexpr (MODE == 1) {
            ((bf16_t*)Cv)[idx] = (bf16_t)(v + bias[col]);
          } else {
            float* C = (float*)Cv;
            C[idx]   = C[idx] + (v + bias[col]) * ls[col];
          }
        }
      }
    }
  }
}

// --------------------------------------------------------- flash attention
// One block per (64-row Q tile, z = b*16+h). 4 waves, each owning 16 Q rows.
// KV tiles of 128 tokens. S never hits HBM.
__global__ __launch_bounds__(256) void flash_attn(
    const bf16_t* __restrict__ qkv,   // [2][1024][3072] (V region unused)
    const bf16_t* __restrict__ vT,    // [32][64][1024]
    bf16_t* __restrict__ o) {         // [2][1024][1024] col = h*64+d
  constexpr int NT = 128;
  __shared__ __attribute__((aligned(16))) bf16_t Qs[2 * 64 * 32];   // 8 KB
  __shared__ __attribute__((aligned(16))) bf16_t Ks[2 * NT * 32];   // 16 KB
  __shared__ __attribute__((aligned(16))) bf16_t Vs[4 * 64 * 32];   // 16 KB
  __shared__ __attribute__((aligned(16))) bf16_t Ps[4][4 * 16 * 32];// 16 KB

  const int tid = threadIdx.x, lane = tid & 63, wave = tid >> 6;
  const int fm = lane & 15, quad = lane >> 4;
  const int z = blockIdx.y, b = z >> 4, h = z & 15;
  const int q0 = blockIdx.x * 64;
  const bf16_t* qb  = qkv + (size_t)b * 1024 * 3072 + h * 64;
  const bf16_t* kb  = qb + 1024;
  const bf16_t* vtb = vT + (size_t)z * 64 * 1024;

  // stage Q tile: layout [kk(2)][row(64)][32]
  for (int c = tid; c < 512; c += 256) {
    const int kk = c >> 8, rr = (c >> 2) & 63, ii = c & 3;
    load_lds16(qb + (size_t)(q0 + rr) * 3072 + kk * 32 + ii * 8, &Qs[c * 8]);
  }
  __syncthreads();
  bf16x8 qf[2];
  qf[0] = *(const bf16x8*)&Qs[(wave * 16 + fm) * 32 + quad * 8];
  qf[1] = *(const bf16x8*)&Qs[64 * 32 + (wave * 16 + fm) * 32 + quad * 8];

  float mr[4], lr[4];
  f32x4 oacc[4];
#pragma unroll
  for (int r = 0; r < 4; ++r) { mr[r] = -1e30f; lr[r] = 0.f; }
#pragma unroll
  for (int t = 0; t < 4; ++t) oacc[t] = (f32x4){0.f, 0.f, 0.f, 0.f};

  for (int kv0 = 0; kv0 < 1024; kv0 += NT) {
    __syncthreads();  // all waves done reading previous K/V tiles
    // K tile [kk(2)][tok(128)][32]
    for (int c = tid; c < NT * 8; c += 256) {
      const int kk = c >> 9, rr = (c >> 2) & 127, ii = c & 3;
      load_lds16(kb + (size_t)(kv0 + rr) * 3072 + kk * 32 + ii * 8, &Ks[c * 8]);
    }
    // V^T tile [tc(4)][d(64)][32]
    for (int c = tid; c < 1024; c += 256) {
      const int tc = c >> 8, rr = (c >> 2) & 63, ii = c & 3;
      load_lds16(vtb + (size_t)rr * 1024 + kv0 + tc * 32 + ii * 8, &Vs[c * 8]);
    }
    __syncthreads();

    // S = Q @ K^T  (8 column tiles of 16)
    f32x4 sc[8];
#pragma unroll
    for (int nt = 0; nt < 8; ++nt) {
      sc[nt] = (f32x4){0.f, 0.f, 0.f, 0.f};
#pragma unroll
      for (int kk = 0; kk < 2; ++kk) {
        const bf16x8 kf =
            *(const bf16x8*)&Ks[kk * NT * 32 + (nt * 16 + fm) * 32 + quad * 8];
        sc[nt] = __builtin_amdgcn_mfma_f32_16x16x32_bf16(qf[kk], kf, sc[nt],
                                                         0, 0, 0);
      }
    }
    // online softmax over this tile (rows = quad*4+r, cols across 16 lanes)
    float tmax[4] = {-1e30f, -1e30f, -1e30f, -1e30f};
#pragma unroll
    for (int nt = 0; nt < 8; ++nt)
#pragma unroll
      for (int r = 0; r < 4; ++r) {
        sc[nt][r] *= SCALE;
        tmax[r] = fmaxf(tmax[r], sc[nt][r]);
      }
#pragma unroll
    for (int m = 1; m < 16; m <<= 1)
#pragma unroll
      for (int r = 0; r < 4; ++r)
        tmax[r] = fmaxf(tmax[r], __shfl_xor(tmax[r], m, 64));
    float alpha[4], mn[4], ps[4];
#pragma unroll
    for (int r = 0; r < 4; ++r) {
      mn[r]    = fmaxf(mr[r], tmax[r]);
      alpha[r] = __expf(mr[r] - mn[r]);
      mr[r]    = mn[r];
      ps[r]    = 0.f;
    }
    // P = exp(S - m); write to per-wave LDS in [kk(4)][m(16)][32] layout
#pragma unroll
    for (int nt = 0; nt < 8; ++nt) {
      const int tcol = nt * 16 + fm, kk = tcol >> 5, tw = tcol & 31;
#pragma unroll
      for (int r = 0; r < 4; ++r) {
        const float p = __expf(sc[nt][r] - mn[r]);
        ps[r] += p;
        Ps[wave][kk * 512 + (quad * 4 + r) * 32 + tw] = (bf16_t)p;
      }
    }
#pragma unroll
    for (int m = 1; m < 16; m <<= 1)
#pragma unroll
      for (int r = 0; r < 4; ++r) ps[r] += __shfl_xor(ps[r], m, 64);
#pragma unroll
    for (int r = 0; r < 4; ++r) lr[r] = lr[r] * alpha[r] + ps[r];
#pragma unroll
    for (int t = 0; t < 4; ++t)
#pragma unroll
      for (int r = 0; r < 4; ++r) oacc[t][r] *= alpha[r];
    // drain this wave's LDS writes of P before reading fragments
    __builtin_amdgcn_s_waitcnt(0xC07F);  // lgkmcnt(0), vm/exp unconstrained
    // O += P @ V
#pragma unroll
    for (int kk = 0; kk < 4; ++kk) {
      const bf16x8 af =
          *(const bf16x8*)&Ps[wave][kk * 512 + fm * 32 + quad * 8];
#pragma unroll
      for (int t = 0; t < 4; ++t) {
        const bf16x8 vf =
            *(const bf16x8*)&Vs[kk * 64 * 32 + (t * 16 + fm) * 32 + quad * 8];
        oacc[t] = __builtin_amdgcn_mfma_f32_16x16x32_bf16(af, vf, oacc[t],
                                                          0, 0, 0);
      }
    }
  }

  // epilogue: normalize and store (C layout)
  const size_t orow0 = (size_t)b * 1024 + q0 + wave * 16 + quad * 4;
#pragma unroll
  for (int t = 0; t < 4; ++t) {
    const int col = h * 64 + t * 16 + fm;
#pragma unroll
    for (int r = 0; r < 4; ++r)
      o[(orow0 + r) * 1024 + col] = (bf16_t)(oacc[t][r] / lr[r]);
  }
}

// --------------------------------------- fused weight transpose+cast (x4)
// One launch per layer handles all four weights. 32x32 fp32->bf16 tiles.
// Segment table (block-uniform branch):
//   s0: wqkv [1024][3072] -> wqkvT          (3072 blocks)
//   s1: wout [1024][1024] -> woutT          (1024 blocks)
//   s2: wff1 [1024][8192] -> wff1T PERMUTED (8192 blocks)
//       dst row for a-col n(<4096): ((n>>4)<<5) + (n&15)
//       dst row for g-col n(>=4096): n'=n-4096 -> ((n'>>4)<<5) + 16 + (n'&15)
//       => 16-wide a/g interleave so GEMM frag pairs align (MODE 3).
//   s3: wff2 [4096][1024] -> wff2T          (4096 blocks)
__global__ __launch_bounds__(256) void transpose_all(
    const float* __restrict__ wqkv, const float* __restrict__ wout,
    const float* __restrict__ wff1, const float* __restrict__ wff2,
    bf16_t* __restrict__ wqkvT, bf16_t* __restrict__ woutT,
    bf16_t* __restrict__ wff1T, bf16_t* __restrict__ wff2T, int l) {
  __shared__ float t[32][33];
  int bx = blockIdx.x;
  const float* W;
  bf16_t*      WT;
  int N, K;
  bool perm = false;
  if (bx < 3072) {
    W = wqkv + (size_t)l * 1024 * 3072; WT = wqkvT; K = 1024; N = 3072;
  } else if (bx < 4096) {
    bx -= 3072;
    W = wout + (size_t)l * 1024 * 1024; WT = woutT; K = 1024; N = 1024;
  } else if (bx < 12288) {
    bx -= 4096;
    W = wff1 + (size_t)l * 1024 * 8192; WT = wff1T; K = 1024; N = 8192;
    perm = true;
  } else {
    bx -= 12288;
    W = wff2 + (size_t)l * 4096 * 1024; WT = wff2T; K = 4096; N = 1024;
  }
  const int nbx = N >> 5;
  const int n0 = (bx % nbx) * 32, k0 = (bx / nbx) * 32;
  const int tx = threadIdx.x & 31, ty = threadIdx.x >> 5;
#pragma unroll
  for (int s = 0; s < 4; ++s)
    t[ty + 8 * s][tx] = W[(size_t)(k0 + ty + 8 * s) * N + n0 + tx];
  __syncthreads();
#pragma unroll
  for (int s = 0; s < 4; ++s) {
    const int n = n0 + ty + 8 * s;
    int r;
    if (perm)
      r = (n < 4096) ? (((n >> 4) << 5) + (n & 15))
                     : ((((n - 4096) >> 4) << 5) + 16 + (n & 15));
    else
      r = n;
    WT[(size_t)r * K + k0 + tx] = (bf16_t)t[tx][ty + 8 * s];
  }
}

// -------------------------------------------------------------- layernorm
__global__ __launch_bounds__(256) void ln_kernel(const float* __restrict__ x,
                                                 const float* __restrict__ w,
                                                 const float* __restrict__ b,
                                                 bf16_t* __restrict__ out) {
  __shared__ float sb[4];
  const int row = blockIdx.x, tid = threadIdx.x;
  const float4 v = ((const float4*)(x + (size_t)row * DIM))[tid];
  float s = v.x + v.y + v.z + v.w;
  s = block_sum(s, sb);
  const float mu = s * (1.f / DIM);
  const float dx = v.x - mu, dy = v.y - mu, dz = v.z - mu, dw = v.w - mu;
  float q = dx * dx + dy * dy + dz * dz + dw * dw;
  q = block_sum(q, sb);
  const float rstd = rsqrtf(q * (1.f / DIM) + 1e-5f);
  const float4 wv = ((const float4*)w)[tid];
  const float4 bv = ((const float4*)b)[tid];
  bf16x4 o;
  o[0] = (bf16_t)(dx * rstd * wv.x + bv.x);
  o[1] = (bf16_t)(dy * rstd * wv.y + bv.y);
  o[2] = (bf16_t)(dz * rstd * wv.z + bv.z);
  o[3] = (bf16_t)(dw * rstd * wv.w + bv.w);
  ((bf16x4*)(out + (size_t)row * DIM))[tid] = o;
}

// ------------------------------------------------------------------ launch
extern "C" void kernel_launch(void* const* d_in, const int* in_sizes, int n_in,
                              void* d_out, int out_size, void* d_ws,
                              size_t ws_size, hipStream_t stream) {
  const float* x_in = (const float*)d_in[0];
  const float* ln1w = (const float*)d_in[1];
  const float* ln1b = (const float*)d_in[2];
  const float* wqkv = (const float*)d_in[3];
  const float* wout = (const float*)d_in[4];
  const float* bout = (const float*)d_in[5];
  const float* ls1  = (const float*)d_in[6];
  const float* ln2w = (const float*)d_in[7];
  const float* ln2b = (const float*)d_in[8];
  const float* wff1 = (const float*)d_in[9];
  const float* bff1 = (const float*)d_in[10];
  const float* wff2 = (const float*)d_in[11];
  const float* bff2 = (const float*)d_in[12];
  const float* ls2  = (const float*)d_in[13];
  float*       xout = (float*)d_out;

  // -------- workspace carve-up (~76 MB)
  char*   ws     = (char*)d_ws;
  bf16_t* wqkvT  = (bf16_t*)ws; ws += (size_t)3072 * 1024 * 2;   // 6.3 MB
  bf16_t* woutT  = (bf16_t*)ws; ws += (size_t)1024 * 1024 * 2;   // 2.1 MB
  bf16_t* wff1T  = (bf16_t*)ws; ws += (size_t)8192 * 1024 * 2;   // 16.8 MB
  bf16_t* wff2T  = (bf16_t*)ws; ws += (size_t)1024 * 4096 * 2;   // 8.4 MB
  bf16_t* h_bf   = (bf16_t*)ws; ws += (size_t)MROWS * 1024 * 2;  // 4.2 MB
  bf16_t* qkv_bf = (bf16_t*)ws; ws += (size_t)MROWS * 3072 * 2;  // 12.6 MB
  bf16_t* o_bf   = (bf16_t*)ws; ws += (size_t)MROWS * 1024 * 2;  // 4.2 MB
  bf16_t* vT     = (bf16_t*)ws; ws += (size_t)32 * 64 * 1024 * 2;// 4.2 MB
  bf16_t* ff_bf  = (bf16_t*)ws; ws += (size_t)MROWS * 4096 * 2;  // 16.8 MB
  if (ws_size < (size_t)(ws - (char*)d_ws)) return;  // visible fail

  hipMemcpyAsync(xout, x_in, (size_t)MROWS * DIM * 4,
                 hipMemcpyDeviceToDevice, stream);

  for (int l = 0; l < 4; ++l) {
    // ---- all four weight transposes in one launch
    transpose_all<<<dim3(16384), 256, 0, stream>>>(
        wqkv, wout, wff1, wff2, wqkvT, woutT, wff1T, wff2T, l);

    // ---- attention
    ln_kernel<<<MROWS, 256, 0, stream>>>(xout, ln1w + l * 1024,
                                         ln1b + l * 1024, h_bf);
    // qkv GEMM; V columns go straight to vT (transposed) in the epilogue
    gemm_bt<128, 128, 2, 2, 4><<<dim3(24, 16, 1), 256, 0, stream>>>(
        h_bf, 0, 0, 1024, wqkvT, 0, 0, 1024, qkv_bf, 0, 0, 3072, 1024, 1.f,
        nullptr, nullptr, vT);
    flash_attn<<<dim3(16, 32), 256, 0, stream>>>(qkv_bf, vT, o_bf);
    // x += (o @ w_out + b_out) * ls1   (256 blocks: 64x128 tiles)
    gemm_bt<64, 128, 1, 4, 2><<<dim3(8, 32, 1), 256, 0, stream>>>(
        o_bf, 0, 0, 1024, woutT, 0, 0, 1024, xout, 0, 0, 1024, 1024, 1.f,
        bout + l * 1024, ls1 + l * 1024, nullptr);

    // ---- feedforward (GEGLU fused into ff1 epilogue via permuted wff1T)
    ln_kernel<<<MROWS, 256, 0, stream>>>(xout, ln2w + l * 1024,
                                         ln2b + l * 1024, h_bf);
    gemm_bt<128, 128, 2, 2, 3><<<dim3(64, 16, 1), 256, 0, stream>>>(
        h_bf, 0, 0, 1024, wff1T, 0, 0, 1024, ff_bf, 0, 0, 4096, 1024, 1.f,
        bff1 + l * 8192, nullptr, nullptr);
    // x += (ff @ w_ff2 + b_ff2) * ls2  (256 blocks: 64x128 tiles)
    gemm_bt<64, 128, 1, 4, 2><<<dim3(8, 32, 1), 256, 0, stream>>>(
        ff_bf, 0, 0, 4096, wff2T, 0, 0, 4096, xout, 0, 0, 1024, 4096, 1.f,
        bff2 + l * 1024, ls2 + l * 1024, nullptr);
  }
}

// Round 3
// 1134.225 us; speedup vs baseline: 1.0805x; 1.0391x over previous
//
#include <hip/hip_runtime.h>
#include <cstdint>
#include <cstddef>

// ---------------------------------------------------------------- types
typedef __bf16 bf16_t;
typedef __bf16 bf16x8 __attribute__((ext_vector_type(8)));
typedef __bf16 bf16x4 __attribute__((ext_vector_type(4)));
typedef float  f32x4  __attribute__((ext_vector_type(4)));

#define DEV __device__ __forceinline__

static constexpr int   BATCH = 2;
static constexpr int   NTOK  = 1024;
static constexpr int   DIM   = 1024;
static constexpr int   MROWS = BATCH * NTOK;      // 2048 token rows
static constexpr float SCALE = 0.125f;            // 64^-0.5

// ------------------------------------------------------- global->LDS DMA
DEV void load_lds16(const bf16_t* g, bf16_t* s) {
  __builtin_amdgcn_global_load_lds(
      (const __attribute__((address_space(1))) void*)g,
      (__attribute__((address_space(3))) void*)s, 16, 0, 0);
}

// ------------------------------------------------------------ reductions
DEV float wave_sum(float v) {
#pragma unroll
  for (int m = 1; m < 64; m <<= 1) v += __shfl_xor(v, m, 64);
  return v;
}
DEV float block_sum(float v, float* sb) {
  v = wave_sum(v);
  __syncthreads();
  if ((threadIdx.x & 63) == 0) sb[threadIdx.x >> 6] = v;
  __syncthreads();
  return sb[0] + sb[1] + sb[2] + sb[3];
}

// ------------------------------------------------------------------ GEMM
// C[M,N] = A[M,K] @ B[K,N], with B given transposed: BT[N][K] (row-major).
// Fragment layout (verified):
//   A frag:  A[m = lane&15][k = (lane>>4)*8 + j]   -> 8 contiguous bf16
//   B frag:  BT[n = lane&15][k = (lane>>4)*8 + j]  -> 8 contiguous bf16
//   C/D:     col = lane&15, row = (lane>>4)*4 + reg
// MODE 0: C(bf16) = alpha * acc
// MODE 1: C(bf16) = acc + bias[col]
// MODE 2: C(f32) += (acc + bias[col]) * ls[col]   (residual update in place)
// MODE 4: QKV epilogue. cols < 2048 (Q,K) -> C as bf16; cols >= 2048 (V)
//         -> vtp[z=b*16+h][d][tok] transposed store (feeds flash_attn).
template <int BM, int BN, int WR, int WC, int MODE>
__global__ __launch_bounds__(256) void gemm_bt(
    const bf16_t* __restrict__ A, long sA0, long sA1, int lda,
    const bf16_t* __restrict__ B, long sB0, long sB1, int ldb,
    void* __restrict__ Cv, long sC0, long sC1, int ldc,
    int K, float alpha, const float* __restrict__ bias,
    const float* __restrict__ ls, bf16_t* __restrict__ vtp) {
  constexpr int TM = BM / WR / 16;
  constexpr int TN = BN / WC / 16;
  __shared__ __attribute__((aligned(16))) bf16_t As[BM * 32];
  __shared__ __attribute__((aligned(16))) bf16_t Bs[BN * 32];

  const int tid  = threadIdx.x;
  const int lane = tid & 63, wave = tid >> 6;
  const int z  = blockIdx.z;
  const int zh = z >> 4, zl = z & 15;
  A += (size_t)zh * sA0 + (size_t)zl * sA1;
  B += (size_t)zh * sB0 + (size_t)zl * sB1;

  const int m0 = blockIdx.y * BM, n0 = blockIdx.x * BN;
  const int wm = (wave / WC) * (BM / WR);
  const int wn = (wave % WC) * (BN / WC);
  const int fm = lane & 15, quad = lane >> 4;

  f32x4 acc[TM][TN] = {};

  for (int k0 = 0; k0 < K; k0 += 32) {
#pragma unroll
    for (int c = tid; c < BM * 4; c += 256) {
      const int row = c >> 2, kc = (c & 3) << 3;
      load_lds16(A + (size_t)(m0 + row) * lda + k0 + kc, &As[c * 8]);
    }
#pragma unroll
    for (int c = tid; c < BN * 4; c += 256) {
      const int row = c >> 2, kc = (c & 3) << 3;
      load_lds16(B + (size_t)(n0 + row) * ldb + k0 + kc, &Bs[c * 8]);
    }
    __syncthreads();

    bf16x8 af[TM], bfr[TN];
#pragma unroll
    for (int i = 0; i < TM; ++i)
      af[i] = *(const bf16x8*)&As[(wm + i * 16 + fm) * 32 + quad * 8];
#pragma unroll
    for (int j = 0; j < TN; ++j)
      bfr[j] = *(const bf16x8*)&Bs[(wn + j * 16 + fm) * 32 + quad * 8];
#pragma unroll
    for (int i = 0; i < TM; ++i)
#pragma unroll
      for (int j = 0; j < TN; ++j)
        acc[i][j] = __builtin_amdgcn_mfma_f32_16x16x32_bf16(af[i], bfr[j],
                                                            acc[i][j], 0, 0, 0);
    __syncthreads();
  }

  const size_t coff = (size_t)zh * sC0 + (size_t)zl * sC1;
  if constexpr (MODE == 4) {
    bf16_t* C = (bf16_t*)Cv;
#pragma unroll
    for (int i = 0; i < TM; ++i) {
#pragma unroll
      for (int j = 0; j < TN; ++j) {
        const int col  = n0 + wn + j * 16 + fm;
        const int rowb = m0 + wm + i * 16 + quad * 4;
        if (col < 2048) {  // Q,K region: normal bf16 store
#pragma unroll
          for (int r = 0; r < 4; ++r)
            C[(size_t)(rowb + r) * ldc + col] = (bf16_t)acc[i][j][r];
        } else {           // V region: transposed store into vT[z][d][tok]
          const int hh = (col - 2048) >> 6, d = (col - 2048) & 63;
#pragma unroll
          for (int r = 0; r < 4; ++r) {
            const int row = rowb + r, bb = row >> 10, tok = row & 1023;
            vtp[((size_t)(bb * 16 + hh) * 64 + d) * 1024 + tok] =
                (bf16_t)acc[i][j][r];
          }
        }
      }
    }
  } else {
#pragma unroll
    for (int i = 0; i < TM; ++i) {
#pragma unroll
      for (int j = 0; j < TN; ++j) {
        const int col  = n0 + wn + j * 16 + fm;
        const int rowb = m0 + wm + i * 16 + quad * 4;
#pragma unroll
        for (int r = 0; r < 4; ++r) {
          const float  v   = acc[i][j][r];
          const size_t idx = coff + (size_t)(rowb + r) * ldc + col;
          if constexpr (MODE == 0) {
            ((bf16_t*)Cv)[idx] = (bf16_t)(v * alpha);
          } else if constexpr (MODE == 1) {
            ((bf16_t*)Cv)[idx] = (bf16_t)(v + bias[col]);
          } else {
            float* C = (float*)Cv;
            C[idx]   = C[idx] + (v + bias[col]) * ls[col];
          }
        }
      }
    }
  }
}

// ------------------------------------------- 256x256 8-phase GEMM (ff1)
// C[2048][4096] = GEGLU(A[2048][K] @ BT_perm[8192][K] + bias), K=1024.
// BT rows are the a/g 16-interleaved permutation (transpose_all s2), so
// per-wave col-frag pairs (2p, 2p+1) = (a, g) for the same ff column.
//
// Schedule (derived from the verified 256^2 8-phase template, T3+T4+T5):
//   BK=64 per K-tile, split as two K-halves of 32. LDS [2 slot][2 kh][256][32]
//   (32-wide rows = bank-balanced frag reads; linear global_load_lds dest).
//   4 phases/K-tile, gray-code (ks, n-pair); each phase stages ONE 16 KB
//   half-tile; ONE counted vmcnt(6) per K-tile (3 halves in flight);
//   raw s_barrier (no vmcnt(0) drain); setprio(1) around MFMA cluster.
// Coverage invariant (hand-verified): tile t's halves issue at
// (t-2,ph1..ph3)+(t-1,ph0); at (t-1,ph3) 7 stages (14 loads) in flight;
// vmcnt(6) retires oldest 8 = through B[t]kh1 => tile t landed.
// Region safety: every stage is issued after a barrier postdating all
// reads of its target region.
// vmcnt uses asm volatile + "memory" clobber (not the builtin) so LDS
// reads cannot hoist above it at IR level; sched_barrier(0) per rule #18.
__global__ __launch_bounds__(512, 2) void gemm256_ff1(
    const bf16_t* __restrict__ A,    // [2048][K]  h_bf
    const bf16_t* __restrict__ B,    // [8192][K]  wff1T (permuted)
    bf16_t* __restrict__ C,          // [2048][4096] ff_bf
    const float* __restrict__ bias,  // [8192]
    int K) {
  __shared__ __attribute__((aligned(16))) bf16_t As[2][2][256 * 32];
  __shared__ __attribute__((aligned(16))) bf16_t Bs[2][2][256 * 32];

  const int tid = threadIdx.x, lane = tid & 63, wave = tid >> 6;
  const int wm2 = wave >> 2, wn4 = wave & 3;
  const int fm = lane & 15, quad = lane >> 4;
  const int m0 = blockIdx.y * 256, n0 = blockIdx.x * 256;
  const int NK = K >> 6;

  // stage one K-half (256 rows x 32 k) = 2x16B per thread, linear LDS dest
  auto stage = [&](const bf16_t* g, int base, int kt, int kh, bf16_t* s) {
#pragma unroll
    for (int it = 0; it < 2; ++it) {
      const int c = it * 512 + tid, row = c >> 2, kc = (c & 3) << 3;
      load_lds16(g + (size_t)(base + row) * K + kt * 64 + kh * 32 + kc,
                 s + c * 8);
    }
  };

  f32x4 acc[8][4] = {};

  // ---- prologue: tile0 fully + tile1 first 3 halves
  stage(A, m0, 0, 0, &As[0][0][0]);
  stage(B, n0, 0, 0, &Bs[0][0][0]);
  stage(A, m0, 0, 1, &As[0][1][0]);
  stage(B, n0, 0, 1, &Bs[0][1][0]);
  if (NK > 1) {
    stage(A, m0, 1, 0, &As[1][0][0]);
    stage(B, n0, 1, 0, &Bs[1][0][0]);
    stage(A, m0, 1, 1, &As[1][1][0]);
  }
  asm volatile("s_waitcnt vmcnt(6)" ::: "memory");  // tile0 fully landed
  __builtin_amdgcn_sched_barrier(0);
  __builtin_amdgcn_s_barrier();

  const int ar = wm2 * 128 + fm;  // + m*16
  const int br = wn4 * 64 + fm;   // + n*16
  const int qo = quad * 8;

  for (int kt = 0; kt < NK; ++kt) {
    const int cur = kt & 1;
    bf16x8 af[8], b0, b1;

    // ========== phase 0: ks0 x {n0,n1} ==========
#pragma unroll
    for (int m = 0; m < 8; ++m)
      af[m] = *(const bf16x8*)&As[cur][0][(ar + m * 16) * 32 + qo];
    b0 = *(const bf16x8*)&Bs[cur][0][br * 32 + qo];
    b1 = *(const bf16x8*)&Bs[cur][0][(br + 16) * 32 + qo];
    if (kt + 1 < NK) stage(B, n0, kt + 1, 1, &Bs[cur ^ 1][1][0]);
    __builtin_amdgcn_s_barrier();
    __builtin_amdgcn_s_setprio(1);
#pragma unroll
    for (int m = 0; m < 8; ++m) {
      acc[m][0] = __builtin_amdgcn_mfma_f32_16x16x32_bf16(af[m], b0,
                                                          acc[m][0], 0, 0, 0);
      acc[m][1] = __builtin_amdgcn_mfma_f32_16x16x32_bf16(af[m], b1,
                                                          acc[m][1], 0, 0, 0);
    }
    __builtin_amdgcn_s_setprio(0);
    __builtin_amdgcn_s_barrier();

    // ========== phase 1: ks0 x {n2,n3} ==========
    b0 = *(const bf16x8*)&Bs[cur][0][(br + 32) * 32 + qo];
    b1 = *(const bf16x8*)&Bs[cur][0][(br + 48) * 32 + qo];
    if (kt + 2 < NK) stage(A, m0, kt + 2, 0, &As[cur][0][0]);
    __builtin_amdgcn_s_barrier();
    __builtin_amdgcn_s_setprio(1);
#pragma unroll
    for (int m = 0; m < 8; ++m) {
      acc[m][2] = __builtin_amdgcn_mfma_f32_16x16x32_bf16(af[m], b0,
                                                          acc[m][2], 0, 0, 0);
      acc[m][3] = __builtin_amdgcn_mfma_f32_16x16x32_bf16(af[m], b1,
                                                          acc[m][3], 0, 0, 0);
    }
    __builtin_amdgcn_s_setprio(0);
    __builtin_amdgcn_s_barrier();

    // ========== phase 2: ks1 x {n2,n3} ==========
#pragma unroll
    for (int m = 0; m < 8; ++m)
      af[m] = *(const bf16x8*)&As[cur][1][(ar + m * 16) * 32 + qo];
    b0 = *(const bf16x8*)&Bs[cur][1][(br + 32) * 32 + qo];
    b1 = *(const bf16x8*)&Bs[cur][1][(br + 48) * 32 + qo];
    if (kt + 2 < NK) stage(B, n0, kt + 2, 0, &Bs[cur][0][0]);
    __builtin_amdgcn_s_barrier();
    __builtin_amdgcn_s_setprio(1);
#pragma unroll
    for (int m = 0; m < 8; ++m) {
      acc[m][2] = __builtin_amdgcn_mfma_f32_16x16x32_bf16(af[m], b0,
                                                          acc[m][2], 0, 0, 0);
      acc[m][3] = __builtin_amdgcn_mfma_f32_16x16x32_bf16(af[m], b1,
                                                          acc[m][3], 0, 0, 0);
    }
    __builtin_amdgcn_s_setprio(0);
    __builtin_amdgcn_s_barrier();

    // ========== phase 3: ks1 x {n0,n1} ==========
    b0 = *(const bf16x8*)&Bs[cur][1][br * 32 + qo];
    b1 = *(const bf16x8*)&Bs[cur][1][(br + 16) * 32 + qo];
    if (kt + 2 < NK) stage(A, m0, kt + 2, 1, &As[cur][1][0]);
    asm volatile("s_waitcnt vmcnt(6)" ::: "memory");  // tile kt+1 landed
    __builtin_amdgcn_sched_barrier(0);
    __builtin_amdgcn_s_barrier();
    __builtin_amdgcn_s_setprio(1);
#pragma unroll
    for (int m = 0; m < 8; ++m) {
      acc[m][0] = __builtin_amdgcn_mfma_f32_16x16x32_bf16(af[m], b0,
                                                          acc[m][0], 0, 0, 0);
      acc[m][1] = __builtin_amdgcn_mfma_f32_16x16x32_bf16(af[m], b1,
                                                          acc[m][1], 0, 0, 0);
    }
    __builtin_amdgcn_s_setprio(0);
    __builtin_amdgcn_s_barrier();
  }

  // ---- GEGLU epilogue: pairs (acc[m][2p], acc[m][2p+1]) = (a, g)
#pragma unroll
  for (int m = 0; m < 8; ++m) {
    const int rowb = m0 + wm2 * 128 + m * 16 + quad * 4;
#pragma unroll
    for (int p = 0; p < 2; ++p) {
      const int   cf = ((n0 + wn4 * 64 + p * 32) >> 1) + fm;
      const float ba = bias[cf], bg = bias[4096 + cf];
#pragma unroll
      for (int r = 0; r < 4; ++r) {
        const float a  = acc[m][2 * p][r] + ba;
        const float g  = acc[m][2 * p + 1][r] + bg;
        const float ge = 0.5f * g * (1.f + erff(g * 0.70710678118654752f));
        C[(size_t)(rowb + r) * 4096 + cf] = (bf16_t)(a * ge);
      }
    }
  }
}

// --------------------------------------------------------- flash attention
// One block per (64-row Q tile, z = b*16+h). 4 waves, each owning 16 Q rows.
// KV tiles of 128 tokens. S never hits HBM.
__global__ __launch_bounds__(256) void flash_attn(
    const bf16_t* __restrict__ qkv,   // [2][1024][3072] (V region unused)
    const bf16_t* __restrict__ vT,    // [32][64][1024]
    bf16_t* __restrict__ o) {         // [2][1024][1024] col = h*64+d
  constexpr int NT = 128;
  __shared__ __attribute__((aligned(16))) bf16_t Qs[2 * 64 * 32];   // 8 KB
  __shared__ __attribute__((aligned(16))) bf16_t Ks[2 * NT * 32];   // 16 KB
  __shared__ __attribute__((aligned(16))) bf16_t Vs[4 * 64 * 32];   // 16 KB
  __shared__ __attribute__((aligned(16))) bf16_t Ps[4][4 * 16 * 32];// 16 KB

  const int tid = threadIdx.x, lane = tid & 63, wave = tid >> 6;
  const int fm = lane & 15, quad = lane >> 4;
  const int z = blockIdx.y, b = z >> 4, h = z & 15;
  const int q0 = blockIdx.x * 64;
  const bf16_t* qb  = qkv + (size_t)b * 1024 * 3072 + h * 64;
  const bf16_t* kb  = qb + 1024;
  const bf16_t* vtb = vT + (size_t)z * 64 * 1024;

  // stage Q tile: layout [kk(2)][row(64)][32]
  for (int c = tid; c < 512; c += 256) {
    const int kk = c >> 8, rr = (c >> 2) & 63, ii = c & 3;
    load_lds16(qb + (size_t)(q0 + rr) * 3072 + kk * 32 + ii * 8, &Qs[c * 8]);
  }
  __syncthreads();
  bf16x8 qf[2];
  qf[0] = *(const bf16x8*)&Qs[(wave * 16 + fm) * 32 + quad * 8];
  qf[1] = *(const bf16x8*)&Qs[64 * 32 + (wave * 16 + fm) * 32 + quad * 8];

  float mr[4], lr[4];
  f32x4 oacc[4];
#pragma unroll
  for (int r = 0; r < 4; ++r) { mr[r] = -1e30f; lr[r] = 0.f; }
#pragma unroll
  for (int t = 0; t < 4; ++t) oacc[t] = (f32x4){0.f, 0.f, 0.f, 0.f};

  for (int kv0 = 0; kv0 < 1024; kv0 += NT) {
    __syncthreads();  // all waves done reading previous K/V tiles
    // K tile [kk(2)][tok(128)][32]
    for (int c = tid; c < NT * 8; c += 256) {
      const int kk = c >> 9, rr = (c >> 2) & 127, ii = c & 3;
      load_lds16(kb + (size_t)(kv0 + rr) * 3072 + kk * 32 + ii * 8, &Ks[c * 8]);
    }
    // V^T tile [tc(4)][d(64)][32]
    for (int c = tid; c < 1024; c += 256) {
      const int tc = c >> 8, rr = (c >> 2) & 63, ii = c & 3;
      load_lds16(vtb + (size_t)rr * 1024 + kv0 + tc * 32 + ii * 8, &Vs[c * 8]);
    }
    __syncthreads();

    // S = Q @ K^T  (8 column tiles of 16)
    f32x4 sc[8];
#pragma unroll
    for (int nt = 0; nt < 8; ++nt) {
      sc[nt] = (f32x4){0.f, 0.f, 0.f, 0.f};
#pragma unroll
      for (int kk = 0; kk < 2; ++kk) {
        const bf16x8 kf =
            *(const bf16x8*)&Ks[kk * NT * 32 + (nt * 16 + fm) * 32 + quad * 8];
        sc[nt] = __builtin_amdgcn_mfma_f32_16x16x32_bf16(qf[kk], kf, sc[nt],
                                                         0, 0, 0);
      }
    }
    // online softmax over this tile (rows = quad*4+r, cols across 16 lanes)
    float tmax[4] = {-1e30f, -1e30f, -1e30f, -1e30f};
#pragma unroll
    for (int nt = 0; nt < 8; ++nt)
#pragma unroll
      for (int r = 0; r < 4; ++r) {
        sc[nt][r] *= SCALE;
        tmax[r] = fmaxf(tmax[r], sc[nt][r]);
      }
#pragma unroll
    for (int m = 1; m < 16; m <<= 1)
#pragma unroll
      for (int r = 0; r < 4; ++r)
        tmax[r] = fmaxf(tmax[r], __shfl_xor(tmax[r], m, 64));
    float alpha[4], mn[4], ps[4];
#pragma unroll
    for (int r = 0; r < 4; ++r) {
      mn[r]    = fmaxf(mr[r], tmax[r]);
      alpha[r] = __expf(mr[r] - mn[r]);
      mr[r]    = mn[r];
      ps[r]    = 0.f;
    }
    // P = exp(S - m); write to per-wave LDS in [kk(4)][m(16)][32] layout
#pragma unroll
    for (int nt = 0; nt < 8; ++nt) {
      const int tcol = nt * 16 + fm, kk = tcol >> 5, tw = tcol & 31;
#pragma unroll
      for (int r = 0; r < 4; ++r) {
        const float p = __expf(sc[nt][r] - mn[r]);
        ps[r] += p;
        Ps[wave][kk * 512 + (quad * 4 + r) * 32 + tw] = (bf16_t)p;
      }
    }
#pragma unroll
    for (int m = 1; m < 16; m <<= 1)
#pragma unroll
      for (int r = 0; r < 4; ++r) ps[r] += __shfl_xor(ps[r], m, 64);
#pragma unroll
    for (int r = 0; r < 4; ++r) lr[r] = lr[r] * alpha[r] + ps[r];
#pragma unroll
    for (int t = 0; t < 4; ++t)
#pragma unroll
      for (int r = 0; r < 4; ++r) oacc[t][r] *= alpha[r];
    // drain this wave's LDS writes of P before reading fragments
    __builtin_amdgcn_s_waitcnt(0xC07F);  // lgkmcnt(0), vm/exp unconstrained
    // O += P @ V
#pragma unroll
    for (int kk = 0; kk < 4; ++kk) {
      const bf16x8 af =
          *(const bf16x8*)&Ps[wave][kk * 512 + fm * 32 + quad * 8];
#pragma unroll
      for (int t = 0; t < 4; ++t) {
        const bf16x8 vf =
            *(const bf16x8*)&Vs[kk * 64 * 32 + (t * 16 + fm) * 32 + quad * 8];
        oacc[t] = __builtin_amdgcn_mfma_f32_16x16x32_bf16(af, vf, oacc[t],
                                                          0, 0, 0);
      }
    }
  }

  // epilogue: normalize and store (C layout)
  const size_t orow0 = (size_t)b * 1024 + q0 + wave * 16 + quad * 4;
#pragma unroll
  for (int t = 0; t < 4; ++t) {
    const int col = h * 64 + t * 16 + fm;
#pragma unroll
    for (int r = 0; r < 4; ++r)
      o[(orow0 + r) * 1024 + col] = (bf16_t)(oacc[t][r] / lr[r]);
  }
}

// --------------------------------------- fused weight transpose+cast (x4)
// One launch per layer handles all four weights. 32x32 fp32->bf16 tiles.
// Segment table (block-uniform branch):
//   s0: wqkv [1024][3072] -> wqkvT          (3072 blocks)
//   s1: wout [1024][1024] -> woutT          (1024 blocks)
//   s2: wff1 [1024][8192] -> wff1T PERMUTED (8192 blocks)
//       dst row for a-col n(<4096): ((n>>4)<<5) + (n&15)
//       dst row for g-col n(>=4096): n'=n-4096 -> ((n'>>4)<<5) + 16 + (n'&15)
//       => 16-wide a/g interleave so GEMM frag pairs align.
//   s3: wff2 [4096][1024] -> wff2T          (4096 blocks)
__global__ __launch_bounds__(256) void transpose_all(
    const float* __restrict__ wqkv, const float* __restrict__ wout,
    const float* __restrict__ wff1, const float* __restrict__ wff2,
    bf16_t* __restrict__ wqkvT, bf16_t* __restrict__ woutT,
    bf16_t* __restrict__ wff1T, bf16_t* __restrict__ wff2T, int l) {
  __shared__ float t[32][33];
  int bx = blockIdx.x;
  const float* W;
  bf16_t*      WT;
  int N, K;
  bool perm = false;
  if (bx < 3072) {
    W = wqkv + (size_t)l * 1024 * 3072; WT = wqkvT; K = 1024; N = 3072;
  } else if (bx < 4096) {
    bx -= 3072;
    W = wout + (size_t)l * 1024 * 1024; WT = woutT; K = 1024; N = 1024;
  } else if (bx < 12288) {
    bx -= 4096;
    W = wff1 + (size_t)l * 1024 * 8192; WT = wff1T; K = 1024; N = 8192;
    perm = true;
  } else {
    bx -= 12288;
    W = wff2 + (size_t)l * 4096 * 1024; WT = wff2T; K = 4096; N = 1024;
  }
  const int nbx = N >> 5;
  const int n0 = (bx % nbx) * 32, k0 = (bx / nbx) * 32;
  const int tx = threadIdx.x & 31, ty = threadIdx.x >> 5;
#pragma unroll
  for (int s = 0; s < 4; ++s)
    t[ty + 8 * s][tx] = W[(size_t)(k0 + ty + 8 * s) * N + n0 + tx];
  __syncthreads();
#pragma unroll
  for (int s = 0; s < 4; ++s) {
    const int n = n0 + ty + 8 * s;
    int r;
    if (perm)
      r = (n < 4096) ? (((n >> 4) << 5) + (n & 15))
                     : ((((n - 4096) >> 4) << 5) + 16 + (n & 15));
    else
      r = n;
    WT[(size_t)r * K + k0 + tx] = (bf16_t)t[tx][ty + 8 * s];
  }
}

// -------------------------------------------------------------- layernorm
__global__ __launch_bounds__(256) void ln_kernel(const float* __restrict__ x,
                                                 const float* __restrict__ w,
                                                 const float* __restrict__ b,
                                                 bf16_t* __restrict__ out) {
  __shared__ float sb[4];
  const int row = blockIdx.x, tid = threadIdx.x;
  const float4 v = ((const float4*)(x + (size_t)row * DIM))[tid];
  float s = v.x + v.y + v.z + v.w;
  s = block_sum(s, sb);
  const float mu = s * (1.f / DIM);
  const float dx = v.x - mu, dy = v.y - mu, dz = v.z - mu, dw = v.w - mu;
  float q = dx * dx + dy * dy + dz * dz + dw * dw;
  q = block_sum(q, sb);
  const float rstd = rsqrtf(q * (1.f / DIM) + 1e-5f);
  const float4 wv = ((const float4*)w)[tid];
  const float4 bv = ((const float4*)b)[tid];
  bf16x4 o;
  o[0] = (bf16_t)(dx * rstd * wv.x + bv.x);
  o[1] = (bf16_t)(dy * rstd * wv.y + bv.y);
  o[2] = (bf16_t)(dz * rstd * wv.z + bv.z);
  o[3] = (bf16_t)(dw * rstd * wv.w + bv.w);
  ((bf16x4*)(out + (size_t)row * DIM))[tid] = o;
}

// ------------------------------------------------------------------ launch
extern "C" void kernel_launch(void* const* d_in, const int* in_sizes, int n_in,
                              void* d_out, int out_size, void* d_ws,
                              size_t ws_size, hipStream_t stream) {
  const float* x_in = (const float*)d_in[0];
  const float* ln1w = (const float*)d_in[1];
  const float* ln1b = (const float*)d_in[2];
  const float* wqkv = (const float*)d_in[3];
  const float* wout = (const float*)d_in[4];
  const float* bout = (const float*)d_in[5];
  const float* ls1  = (const float*)d_in[6];
  const float* ln2w = (const float*)d_in[7];
  const float* ln2b = (const float*)d_in[8];
  const float* wff1 = (const float*)d_in[9];
  const float* bff1 = (const float*)d_in[10];
  const float* wff2 = (const float*)d_in[11];
  const float* bff2 = (const float*)d_in[12];
  const float* ls2  = (const float*)d_in[13];
  float*       xout = (float*)d_out;

  // -------- workspace carve-up (~76 MB)
  char*   ws     = (char*)d_ws;
  bf16_t* wqkvT  = (bf16_t*)ws; ws += (size_t)3072 * 1024 * 2;   // 6.3 MB
  bf16_t* woutT  = (bf16_t*)ws; ws += (size_t)1024 * 1024 * 2;   // 2.1 MB
  bf16_t* wff1T  = (bf16_t*)ws; ws += (size_t)8192 * 1024 * 2;   // 16.8 MB
  bf16_t* wff2T  = (bf16_t*)ws; ws += (size_t)1024 * 4096 * 2;   // 8.4 MB
  bf16_t* h_bf   = (bf16_t*)ws; ws += (size_t)MROWS * 1024 * 2;  // 4.2 MB
  bf16_t* qkv_bf = (bf16_t*)ws; ws += (size_t)MROWS * 3072 * 2;  // 12.6 MB
  bf16_t* o_bf   = (bf16_t*)ws; ws += (size_t)MROWS * 1024 * 2;  // 4.2 MB
  bf16_t* vT     = (bf16_t*)ws; ws += (size_t)32 * 64 * 1024 * 2;// 4.2 MB
  bf16_t* ff_bf  = (bf16_t*)ws; ws += (size_t)MROWS * 4096 * 2;  // 16.8 MB
  if (ws_size < (size_t)(ws - (char*)d_ws)) return;  // visible fail

  hipMemcpyAsync(xout, x_in, (size_t)MROWS * DIM * 4,
                 hipMemcpyDeviceToDevice, stream);

  for (int l = 0; l < 4; ++l) {
    // ---- all four weight transposes in one launch
    transpose_all<<<dim3(16384), 256, 0, stream>>>(
        wqkv, wout, wff1, wff2, wqkvT, woutT, wff1T, wff2T, l);

    // ---- attention
    ln_kernel<<<MROWS, 256, 0, stream>>>(xout, ln1w + l * 1024,
                                         ln1b + l * 1024, h_bf);
    // qkv GEMM; V columns go straight to vT (transposed) in the epilogue
    gemm_bt<128, 128, 2, 2, 4><<<dim3(24, 16, 1), 256, 0, stream>>>(
        h_bf, 0, 0, 1024, wqkvT, 0, 0, 1024, qkv_bf, 0, 0, 3072, 1024, 1.f,
        nullptr, nullptr, vT);
    flash_attn<<<dim3(16, 32), 256, 0, stream>>>(qkv_bf, vT, o_bf);
    // x += (o @ w_out + b_out) * ls1   (256 blocks: 64x128 tiles)
    gemm_bt<64, 128, 1, 4, 2><<<dim3(8, 32, 1), 256, 0, stream>>>(
        o_bf, 0, 0, 1024, woutT, 0, 0, 1024, xout, 0, 0, 1024, 1024, 1.f,
        bout + l * 1024, ls1 + l * 1024, nullptr);

    // ---- feedforward (GEGLU fused into 256^2 8-phase ff1 GEMM)
    ln_kernel<<<MROWS, 256, 0, stream>>>(xout, ln2w + l * 1024,
                                         ln2b + l * 1024, h_bf);
    gemm256_ff1<<<dim3(32, 8), 512, 0, stream>>>(
        h_bf, wff1T, ff_bf, bff1 + l * 8192, 1024);
    // x += (ff @ w_ff2 + b_ff2) * ls2  (256 blocks: 64x128 tiles)
    gemm_bt<64, 128, 1, 4, 2><<<dim3(8, 32, 1), 256, 0, stream>>>(
        ff_bf, 0, 0, 4096, wff2T, 0, 0, 4096, xout, 0, 0, 1024, 4096, 1.f,
        bff2 + l * 1024, ls2 + l * 1024, nullptr);
  }
}

// Round 4
// 1108.604 us; speedup vs baseline: 1.1055x; 1.0231x over previous
//
#include <hip/hip_runtime.h>
#include <cstdint>
#include <cstddef>

// ---------------------------------------------------------------- types
typedef __bf16 bf16_t;
typedef __bf16 bf16x8 __attribute__((ext_vector_type(8)));
typedef __bf16 bf16x4 __attribute__((ext_vector_type(4)));
typedef float  f32x4  __attribute__((ext_vector_type(4)));

#define DEV __device__ __forceinline__

static constexpr int   BATCH = 2;
static constexpr int   NTOK  = 1024;
static constexpr int   DIM   = 1024;
static constexpr int   MROWS = BATCH * NTOK;      // 2048 token rows
static constexpr float SCALE = 0.125f;            // 64^-0.5

// ------------------------------------------------------- global->LDS DMA
DEV void load_lds16(const bf16_t* g, bf16_t* s) {
  __builtin_amdgcn_global_load_lds(
      (const __attribute__((address_space(1))) void*)g,
      (__attribute__((address_space(3))) void*)s, 16, 0, 0);
}

// ------------------------------------------------------------ reductions
DEV float wave_sum(float v) {
#pragma unroll
  for (int m = 1; m < 64; m <<= 1) v += __shfl_xor(v, m, 64);
  return v;
}
DEV float block_sum(float v, float* sb) {
  v = wave_sum(v);
  __syncthreads();
  if ((threadIdx.x & 63) == 0) sb[threadIdx.x >> 6] = v;
  __syncthreads();
  return sb[0] + sb[1] + sb[2] + sb[3];
}

// ------------------------------------------------------------------ GEMM
// C[M,N] = A[M,K] @ B[K,N], with B given transposed: BT[N][K] (row-major).
// Fragment layout (verified):
//   A frag:  A[m = lane&15][k = (lane>>4)*8 + j]   -> 8 contiguous bf16
//   B frag:  BT[n = lane&15][k = (lane>>4)*8 + j]  -> 8 contiguous bf16
//   C/D:     col = lane&15, row = (lane>>4)*4 + reg
// MODE 0: C(bf16) = alpha * acc
// MODE 1: C(bf16) = acc + bias[col]
// MODE 2: C(f32) += (acc + bias[col]) * ls[col]   (residual update in place)
// MODE 4: QKV epilogue. cols < 2048 (Q,K) -> C as bf16; cols >= 2048 (V)
//         -> vtp[z=b*16+h][d][tok] transposed store (feeds flash_attn).
// MODE 5: split-K residual. blockIdx.z = split; A/B offset via sA1/sB1 =
//         Ksplit; K = Ksplit. C(f32) atomicAdd (acc + (z==0)*bias)*ls.
//         Occupancy fix: 1 block/CU -> S blocks/CU for the skinny GEMMs.
template <int BM, int BN, int WR, int WC, int MODE>
__global__ __launch_bounds__(256) void gemm_bt(
    const bf16_t* __restrict__ A, long sA0, long sA1, int lda,
    const bf16_t* __restrict__ B, long sB0, long sB1, int ldb,
    void* __restrict__ Cv, long sC0, long sC1, int ldc,
    int K, float alpha, const float* __restrict__ bias,
    const float* __restrict__ ls, bf16_t* __restrict__ vtp) {
  constexpr int TM = BM / WR / 16;
  constexpr int TN = BN / WC / 16;
  __shared__ __attribute__((aligned(16))) bf16_t As[BM * 32];
  __shared__ __attribute__((aligned(16))) bf16_t Bs[BN * 32];

  const int tid  = threadIdx.x;
  const int lane = tid & 63, wave = tid >> 6;
  const int z  = blockIdx.z;
  const int zh = z >> 4, zl = z & 15;
  A += (size_t)zh * sA0 + (size_t)zl * sA1;
  B += (size_t)zh * sB0 + (size_t)zl * sB1;

  const int m0 = blockIdx.y * BM, n0 = blockIdx.x * BN;
  const int wm = (wave / WC) * (BM / WR);
  const int wn = (wave % WC) * (BN / WC);
  const int fm = lane & 15, quad = lane >> 4;

  f32x4 acc[TM][TN] = {};

  for (int k0 = 0; k0 < K; k0 += 32) {
#pragma unroll
    for (int c = tid; c < BM * 4; c += 256) {
      const int row = c >> 2, kc = (c & 3) << 3;
      load_lds16(A + (size_t)(m0 + row) * lda + k0 + kc, &As[c * 8]);
    }
#pragma unroll
    for (int c = tid; c < BN * 4; c += 256) {
      const int row = c >> 2, kc = (c & 3) << 3;
      load_lds16(B + (size_t)(n0 + row) * ldb + k0 + kc, &Bs[c * 8]);
    }
    __syncthreads();

    bf16x8 af[TM], bfr[TN];
#pragma unroll
    for (int i = 0; i < TM; ++i)
      af[i] = *(const bf16x8*)&As[(wm + i * 16 + fm) * 32 + quad * 8];
#pragma unroll
    for (int j = 0; j < TN; ++j)
      bfr[j] = *(const bf16x8*)&Bs[(wn + j * 16 + fm) * 32 + quad * 8];
#pragma unroll
    for (int i = 0; i < TM; ++i)
#pragma unroll
      for (int j = 0; j < TN; ++j)
        acc[i][j] = __builtin_amdgcn_mfma_f32_16x16x32_bf16(af[i], bfr[j],
                                                            acc[i][j], 0, 0, 0);
    __syncthreads();
  }

  const size_t coff = (size_t)zh * sC0 + (size_t)zl * sC1;
  if constexpr (MODE == 4) {
    bf16_t* C = (bf16_t*)Cv;
#pragma unroll
    for (int i = 0; i < TM; ++i) {
#pragma unroll
      for (int j = 0; j < TN; ++j) {
        const int col  = n0 + wn + j * 16 + fm;
        const int rowb = m0 + wm + i * 16 + quad * 4;
        if (col < 2048) {  // Q,K region: normal bf16 store
#pragma unroll
          for (int r = 0; r < 4; ++r)
            C[(size_t)(rowb + r) * ldc + col] = (bf16_t)acc[i][j][r];
        } else {           // V region: transposed store into vT[z][d][tok]
          const int hh = (col - 2048) >> 6, d = (col - 2048) & 63;
#pragma unroll
          for (int r = 0; r < 4; ++r) {
            const int row = rowb + r, bb = row >> 10, tok = row & 1023;
            vtp[((size_t)(bb * 16 + hh) * 64 + d) * 1024 + tok] =
                (bf16_t)acc[i][j][r];
          }
        }
      }
    }
  } else if constexpr (MODE == 5) {
    float* C = (float*)Cv;
#pragma unroll
    for (int i = 0; i < TM; ++i) {
#pragma unroll
      for (int j = 0; j < TN; ++j) {
        const int col  = n0 + wn + j * 16 + fm;
        const int rowb = m0 + wm + i * 16 + quad * 4;
        const float lsv = ls[col];
        const float bl  = (zl == 0) ? bias[col] * lsv : 0.f;
#pragma unroll
        for (int r = 0; r < 4; ++r) {
          const size_t idx = (size_t)(rowb + r) * ldc + col;
          atomicAdd(&C[idx], acc[i][j][r] * lsv + bl);
        }
      }
    }
  } else {
#pragma unroll
    for (int i = 0; i < TM; ++i) {
#pragma unroll
      for (int j = 0; j < TN; ++j) {
        const int col  = n0 + wn + j * 16 + fm;
        const int rowb = m0 + wm + i * 16 + quad * 4;
#pragma unroll
        for (int r = 0; r < 4; ++r) {
          const float  v   = acc[i][j][r];
          const size_t idx = coff + (size_t)(rowb + r) * ldc + col;
          if constexpr (MODE == 0) {
            ((bf16_t*)Cv)[idx] = (bf16_t)(v * alpha);
          } else if constexpr (MODE == 1) {
            ((bf16_t*)Cv)[idx] = (bf16_t)(v + bias[col]);
          } else {
            float* C = (float*)Cv;
            C[idx]   = C[idx] + (v + bias[col]) * ls[col];
          }
        }
      }
    }
  }
}

// ------------------------------------------- 256x256 8-phase GEMM (ff1)
// C[2048][4096] = GEGLU(A[2048][K] @ BT_perm[8192][K] + bias), K=1024.
// BT rows are the a/g 16-interleaved permutation (transpose_all s2), so
// per-wave col-frag pairs (2p, 2p+1) = (a, g) for the same ff column.
// Schedule: verified in R3 (counted vmcnt(6), raw barriers, setprio).
__global__ __launch_bounds__(512, 2) void gemm256_ff1(
    const bf16_t* __restrict__ A,    // [2048][K]  h_bf
    const bf16_t* __restrict__ B,    // [8192][K]  wff1T (permuted)
    bf16_t* __restrict__ C,          // [2048][4096] ff_bf
    const float* __restrict__ bias,  // [8192]
    int K) {
  __shared__ __attribute__((aligned(16))) bf16_t As[2][2][256 * 32];
  __shared__ __attribute__((aligned(16))) bf16_t Bs[2][2][256 * 32];

  const int tid = threadIdx.x, lane = tid & 63, wave = tid >> 6;
  const int wm2 = wave >> 2, wn4 = wave & 3;
  const int fm = lane & 15, quad = lane >> 4;
  const int m0 = blockIdx.y * 256, n0 = blockIdx.x * 256;
  const int NK = K >> 6;

  auto stage = [&](const bf16_t* g, int base, int kt, int kh, bf16_t* s) {
#pragma unroll
    for (int it = 0; it < 2; ++it) {
      const int c = it * 512 + tid, row = c >> 2, kc = (c & 3) << 3;
      load_lds16(g + (size_t)(base + row) * K + kt * 64 + kh * 32 + kc,
                 s + c * 8);
    }
  };

  f32x4 acc[8][4] = {};

  stage(A, m0, 0, 0, &As[0][0][0]);
  stage(B, n0, 0, 0, &Bs[0][0][0]);
  stage(A, m0, 0, 1, &As[0][1][0]);
  stage(B, n0, 0, 1, &Bs[0][1][0]);
  if (NK > 1) {
    stage(A, m0, 1, 0, &As[1][0][0]);
    stage(B, n0, 1, 0, &Bs[1][0][0]);
    stage(A, m0, 1, 1, &As[1][1][0]);
  }
  asm volatile("s_waitcnt vmcnt(6)" ::: "memory");  // tile0 fully landed
  __builtin_amdgcn_sched_barrier(0);
  __builtin_amdgcn_s_barrier();

  const int ar = wm2 * 128 + fm;
  const int br = wn4 * 64 + fm;
  const int qo = quad * 8;

  for (int kt = 0; kt < NK; ++kt) {
    const int cur = kt & 1;
    bf16x8 af[8], b0, b1;

    // phase 0: ks0 x {n0,n1}
#pragma unroll
    for (int m = 0; m < 8; ++m)
      af[m] = *(const bf16x8*)&As[cur][0][(ar + m * 16) * 32 + qo];
    b0 = *(const bf16x8*)&Bs[cur][0][br * 32 + qo];
    b1 = *(const bf16x8*)&Bs[cur][0][(br + 16) * 32 + qo];
    if (kt + 1 < NK) stage(B, n0, kt + 1, 1, &Bs[cur ^ 1][1][0]);
    __builtin_amdgcn_s_barrier();
    __builtin_amdgcn_s_setprio(1);
#pragma unroll
    for (int m = 0; m < 8; ++m) {
      acc[m][0] = __builtin_amdgcn_mfma_f32_16x16x32_bf16(af[m], b0,
                                                          acc[m][0], 0, 0, 0);
      acc[m][1] = __builtin_amdgcn_mfma_f32_16x16x32_bf16(af[m], b1,
                                                          acc[m][1], 0, 0, 0);
    }
    __builtin_amdgcn_s_setprio(0);
    __builtin_amdgcn_s_barrier();

    // phase 1: ks0 x {n2,n3}
    b0 = *(const bf16x8*)&Bs[cur][0][(br + 32) * 32 + qo];
    b1 = *(const bf16x8*)&Bs[cur][0][(br + 48) * 32 + qo];
    if (kt + 2 < NK) stage(A, m0, kt + 2, 0, &As[cur][0][0]);
    __builtin_amdgcn_s_barrier();
    __builtin_amdgcn_s_setprio(1);
#pragma unroll
    for (int m = 0; m < 8; ++m) {
      acc[m][2] = __builtin_amdgcn_mfma_f32_16x16x32_bf16(af[m], b0,
                                                          acc[m][2], 0, 0, 0);
      acc[m][3] = __builtin_amdgcn_mfma_f32_16x16x32_bf16(af[m], b1,
                                                          acc[m][3], 0, 0, 0);
    }
    __builtin_amdgcn_s_setprio(0);
    __builtin_amdgcn_s_barrier();

    // phase 2: ks1 x {n2,n3}
#pragma unroll
    for (int m = 0; m < 8; ++m)
      af[m] = *(const bf16x8*)&As[cur][1][(ar + m * 16) * 32 + qo];
    b0 = *(const bf16x8*)&Bs[cur][1][(br + 32) * 32 + qo];
    b1 = *(const bf16x8*)&Bs[cur][1][(br + 48) * 32 + qo];
    if (kt + 2 < NK) stage(B, n0, kt + 2, 0, &Bs[cur][0][0]);
    __builtin_amdgcn_s_barrier();
    __builtin_amdgcn_s_setprio(1);
#pragma unroll
    for (int m = 0; m < 8; ++m) {
      acc[m][2] = __builtin_amdgcn_mfma_f32_16x16x32_bf16(af[m], b0,
                                                          acc[m][2], 0, 0, 0);
      acc[m][3] = __builtin_amdgcn_mfma_f32_16x16x32_bf16(af[m], b1,
                                                          acc[m][3], 0, 0, 0);
    }
    __builtin_amdgcn_s_setprio(0);
    __builtin_amdgcn_s_barrier();

    // phase 3: ks1 x {n0,n1}
    b0 = *(const bf16x8*)&Bs[cur][1][br * 32 + qo];
    b1 = *(const bf16x8*)&Bs[cur][1][(br + 16) * 32 + qo];
    if (kt + 2 < NK) stage(A, m0, kt + 2, 1, &As[cur][1][0]);
    asm volatile("s_waitcnt vmcnt(6)" ::: "memory");  // tile kt+1 landed
    __builtin_amdgcn_sched_barrier(0);
    __builtin_amdgcn_s_barrier();
    __builtin_amdgcn_s_setprio(1);
#pragma unroll
    for (int m = 0; m < 8; ++m) {
      acc[m][0] = __builtin_amdgcn_mfma_f32_16x16x32_bf16(af[m], b0,
                                                          acc[m][0], 0, 0, 0);
      acc[m][1] = __builtin_amdgcn_mfma_f32_16x16x32_bf16(af[m], b1,
                                                          acc[m][1], 0, 0, 0);
    }
    __builtin_amdgcn_s_setprio(0);
    __builtin_amdgcn_s_barrier();
  }

  // GEGLU epilogue: pairs (acc[m][2p], acc[m][2p+1]) = (a, g)
#pragma unroll
  for (int m = 0; m < 8; ++m) {
    const int rowb = m0 + wm2 * 128 + m * 16 + quad * 4;
#pragma unroll
    for (int p = 0; p < 2; ++p) {
      const int   cf = ((n0 + wn4 * 64 + p * 32) >> 1) + fm;
      const float ba = bias[cf], bg = bias[4096 + cf];
#pragma unroll
      for (int r = 0; r < 4; ++r) {
        const float a  = acc[m][2 * p][r] + ba;
        const float g  = acc[m][2 * p + 1][r] + bg;
        const float ge = 0.5f * g * (1.f + erff(g * 0.70710678118654752f));
        C[(size_t)(rowb + r) * 4096 + cf] = (bf16_t)(a * ge);
      }
    }
  }
}

// --------------------------------------------------------- flash attention
// One block per (64-row Q tile, z = b*16+h). 4 waves, each owning 16 Q rows.
// KV tiles of 128 tokens. S never hits HBM.
__global__ __launch_bounds__(256) void flash_attn(
    const bf16_t* __restrict__ qkv,   // [2][1024][3072] (V region unused)
    const bf16_t* __restrict__ vT,    // [32][64][1024]
    bf16_t* __restrict__ o) {         // [2][1024][1024] col = h*64+d
  constexpr int NT = 128;
  __shared__ __attribute__((aligned(16))) bf16_t Qs[2 * 64 * 32];   // 8 KB
  __shared__ __attribute__((aligned(16))) bf16_t Ks[2 * NT * 32];   // 16 KB
  __shared__ __attribute__((aligned(16))) bf16_t Vs[4 * 64 * 32];   // 16 KB
  __shared__ __attribute__((aligned(16))) bf16_t Ps[4][4 * 16 * 32];// 16 KB

  const int tid = threadIdx.x, lane = tid & 63, wave = tid >> 6;
  const int fm = lane & 15, quad = lane >> 4;
  const int z = blockIdx.y, b = z >> 4, h = z & 15;
  const int q0 = blockIdx.x * 64;
  const bf16_t* qb  = qkv + (size_t)b * 1024 * 3072 + h * 64;
  const bf16_t* kb  = qb + 1024;
  const bf16_t* vtb = vT + (size_t)z * 64 * 1024;

  // stage Q tile: layout [kk(2)][row(64)][32]
  for (int c = tid; c < 512; c += 256) {
    const int kk = c >> 8, rr = (c >> 2) & 63, ii = c & 3;
    load_lds16(qb + (size_t)(q0 + rr) * 3072 + kk * 32 + ii * 8, &Qs[c * 8]);
  }
  __syncthreads();
  bf16x8 qf[2];
  qf[0] = *(const bf16x8*)&Qs[(wave * 16 + fm) * 32 + quad * 8];
  qf[1] = *(const bf16x8*)&Qs[64 * 32 + (wave * 16 + fm) * 32 + quad * 8];

  float mr[4], lr[4];
  f32x4 oacc[4];
#pragma unroll
  for (int r = 0; r < 4; ++r) { mr[r] = -1e30f; lr[r] = 0.f; }
#pragma unroll
  for (int t = 0; t < 4; ++t) oacc[t] = (f32x4){0.f, 0.f, 0.f, 0.f};

  for (int kv0 = 0; kv0 < 1024; kv0 += NT) {
    __syncthreads();  // all waves done reading previous K/V tiles
    // K tile [kk(2)][tok(128)][32]
    for (int c = tid; c < NT * 8; c += 256) {
      const int kk = c >> 9, rr = (c >> 2) & 127, ii = c & 3;
      load_lds16(kb + (size_t)(kv0 + rr) * 3072 + kk * 32 + ii * 8, &Ks[c * 8]);
    }
    // V^T tile [tc(4)][d(64)][32]
    for (int c = tid; c < 1024; c += 256) {
      const int tc = c >> 8, rr = (c >> 2) & 63, ii = c & 3;
      load_lds16(vtb + (size_t)rr * 1024 + kv0 + tc * 32 + ii * 8, &Vs[c * 8]);
    }
    __syncthreads();

    // S = Q @ K^T  (8 column tiles of 16)
    f32x4 sc[8];
#pragma unroll
    for (int nt = 0; nt < 8; ++nt) {
      sc[nt] = (f32x4){0.f, 0.f, 0.f, 0.f};
#pragma unroll
      for (int kk = 0; kk < 2; ++kk) {
        const bf16x8 kf =
            *(const bf16x8*)&Ks[kk * NT * 32 + (nt * 16 + fm) * 32 + quad * 8];
        sc[nt] = __builtin_amdgcn_mfma_f32_16x16x32_bf16(qf[kk], kf, sc[nt],
                                                         0, 0, 0);
      }
    }
    // online softmax over this tile (rows = quad*4+r, cols across 16 lanes)
    float tmax[4] = {-1e30f, -1e30f, -1e30f, -1e30f};
#pragma unroll
    for (int nt = 0; nt < 8; ++nt)
#pragma unroll
      for (int r = 0; r < 4; ++r) {
        sc[nt][r] *= SCALE;
        tmax[r] = fmaxf(tmax[r], sc[nt][r]);
      }
#pragma unroll
    for (int m = 1; m < 16; m <<= 1)
#pragma unroll
      for (int r = 0; r < 4; ++r)
        tmax[r] = fmaxf(tmax[r], __shfl_xor(tmax[r], m, 64));
    float alpha[4], mn[4], ps[4];
#pragma unroll
    for (int r = 0; r < 4; ++r) {
      mn[r]    = fmaxf(mr[r], tmax[r]);
      alpha[r] = __expf(mr[r] - mn[r]);
      mr[r]    = mn[r];
      ps[r]    = 0.f;
    }
    // P = exp(S - m); write to per-wave LDS in [kk(4)][m(16)][32] layout
#pragma unroll
    for (int nt = 0; nt < 8; ++nt) {
      const int tcol = nt * 16 + fm, kk = tcol >> 5, tw = tcol & 31;
#pragma unroll
      for (int r = 0; r < 4; ++r) {
        const float p = __expf(sc[nt][r] - mn[r]);
        ps[r] += p;
        Ps[wave][kk * 512 + (quad * 4 + r) * 32 + tw] = (bf16_t)p;
      }
    }
#pragma unroll
    for (int m = 1; m < 16; m <<= 1)
#pragma unroll
      for (int r = 0; r < 4; ++r) ps[r] += __shfl_xor(ps[r], m, 64);
#pragma unroll
    for (int r = 0; r < 4; ++r) lr[r] = lr[r] * alpha[r] + ps[r];
#pragma unroll
    for (int t = 0; t < 4; ++t)
#pragma unroll
      for (int r = 0; r < 4; ++r) oacc[t][r] *= alpha[r];
    // drain this wave's LDS writes of P before reading fragments
    __builtin_amdgcn_s_waitcnt(0xC07F);  // lgkmcnt(0), vm/exp unconstrained
    // O += P @ V
#pragma unroll
    for (int kk = 0; kk < 4; ++kk) {
      const bf16x8 af =
          *(const bf16x8*)&Ps[wave][kk * 512 + fm * 32 + quad * 8];
#pragma unroll
      for (int t = 0; t < 4; ++t) {
        const bf16x8 vf =
            *(const bf16x8*)&Vs[kk * 64 * 32 + (t * 16 + fm) * 32 + quad * 8];
        oacc[t] = __builtin_amdgcn_mfma_f32_16x16x32_bf16(af, vf, oacc[t],
                                                          0, 0, 0);
      }
    }
  }

  // epilogue: normalize and store (C layout)
  const size_t orow0 = (size_t)b * 1024 + q0 + wave * 16 + quad * 4;
#pragma unroll
  for (int t = 0; t < 4; ++t) {
    const int col = h * 64 + t * 16 + fm;
#pragma unroll
    for (int r = 0; r < 4; ++r)
      o[(orow0 + r) * 1024 + col] = (bf16_t)(oacc[t][r] / lr[r]);
  }
}

// --------------------------------- fused weight transpose+cast, ALL layers
// grid (16384, 4): blockIdx.y = layer. 32x32 fp32->bf16 tiles.
//   s0: wqkv [1024][3072] -> wqkvT[l]
//   s1: wout [1024][1024] -> woutT[l]
//   s2: wff1 [1024][8192] -> wff1T[l] PERMUTED (a/g 16-col interleave)
//   s3: wff2 [4096][1024] -> wff2T[l]
__global__ __launch_bounds__(256) void transpose_all(
    const float* __restrict__ wqkv, const float* __restrict__ wout,
    const float* __restrict__ wff1, const float* __restrict__ wff2,
    bf16_t* __restrict__ wqkvT, bf16_t* __restrict__ woutT,
    bf16_t* __restrict__ wff1T, bf16_t* __restrict__ wff2T) {
  __shared__ float t[32][33];
  const int l = blockIdx.y;
  int bx = blockIdx.x;
  const float* W;
  bf16_t*      WT;
  int N, K;
  bool perm = false;
  if (bx < 3072) {
    W = wqkv + (size_t)l * 1024 * 3072;
    WT = wqkvT + (size_t)l * 3072 * 1024; K = 1024; N = 3072;
  } else if (bx < 4096) {
    bx -= 3072;
    W = wout + (size_t)l * 1024 * 1024;
    WT = woutT + (size_t)l * 1024 * 1024; K = 1024; N = 1024;
  } else if (bx < 12288) {
    bx -= 4096;
    W = wff1 + (size_t)l * 1024 * 8192;
    WT = wff1T + (size_t)l * 8192 * 1024; K = 1024; N = 8192;
    perm = true;
  } else {
    bx -= 12288;
    W = wff2 + (size_t)l * 4096 * 1024;
    WT = wff2T + (size_t)l * 1024 * 4096; K = 4096; N = 1024;
  }
  const int nbx = N >> 5;
  const int n0 = (bx % nbx) * 32, k0 = (bx / nbx) * 32;
  const int tx = threadIdx.x & 31, ty = threadIdx.x >> 5;
#pragma unroll
  for (int s = 0; s < 4; ++s)
    t[ty + 8 * s][tx] = W[(size_t)(k0 + ty + 8 * s) * N + n0 + tx];
  __syncthreads();
#pragma unroll
  for (int s = 0; s < 4; ++s) {
    const int n = n0 + ty + 8 * s;
    int r;
    if (perm)
      r = (n < 4096) ? (((n >> 4) << 5) + (n & 15))
                     : ((((n - 4096) >> 4) << 5) + 16 + (n & 15));
    else
      r = n;
    WT[(size_t)r * K + k0 + tx] = (bf16_t)t[tx][ty + 8 * s];
  }
}

// -------------------------------------------------------------- layernorm
__global__ __launch_bounds__(256) void ln_kernel(const float* __restrict__ x,
                                                 const float* __restrict__ w,
                                                 const float* __restrict__ b,
                                                 bf16_t* __restrict__ out) {
  __shared__ float sb[4];
  const int row = blockIdx.x, tid = threadIdx.x;
  const float4 v = ((const float4*)(x + (size_t)row * DIM))[tid];
  float s = v.x + v.y + v.z + v.w;
  s = block_sum(s, sb);
  const float mu = s * (1.f / DIM);
  const float dx = v.x - mu, dy = v.y - mu, dz = v.z - mu, dw = v.w - mu;
  float q = dx * dx + dy * dy + dz * dz + dw * dw;
  q = block_sum(q, sb);
  const float rstd = rsqrtf(q * (1.f / DIM) + 1e-5f);
  const float4 wv = ((const float4*)w)[tid];
  const float4 bv = ((const float4*)b)[tid];
  bf16x4 o;
  o[0] = (bf16_t)(dx * rstd * wv.x + bv.x);
  o[1] = (bf16_t)(dy * rstd * wv.y + bv.y);
  o[2] = (bf16_t)(dz * rstd * wv.z + bv.z);
  o[3] = (bf16_t)(dw * rstd * wv.w + bv.w);
  ((bf16x4*)(out + (size_t)row * DIM))[tid] = o;
}

// ------------------------------------------------------------------ launch
extern "C" void kernel_launch(void* const* d_in, const int* in_sizes, int n_in,
                              void* d_out, int out_size, void* d_ws,
                              size_t ws_size, hipStream_t stream) {
  const float* x_in = (const float*)d_in[0];
  const float* ln1w = (const float*)d_in[1];
  const float* ln1b = (const float*)d_in[2];
  const float* wqkv = (const float*)d_in[3];
  const float* wout = (const float*)d_in[4];
  const float* bout = (const float*)d_in[5];
  const float* ls1  = (const float*)d_in[6];
  const float* ln2w = (const float*)d_in[7];
  const float* ln2b = (const float*)d_in[8];
  const float* wff1 = (const float*)d_in[9];
  const float* bff1 = (const float*)d_in[10];
  const float* wff2 = (const float*)d_in[11];
  const float* bff2 = (const float*)d_in[12];
  const float* ls2  = (const float*)d_in[13];
  float*       xout = (float*)d_out;

  // -------- workspace carve-up (~176 MB; all 4 layers' weights resident)
  char*   ws     = (char*)d_ws;
  bf16_t* wqkvT  = (bf16_t*)ws; ws += (size_t)4 * 3072 * 1024 * 2;  // 25 MB
  bf16_t* woutT  = (bf16_t*)ws; ws += (size_t)4 * 1024 * 1024 * 2;  //  8 MB
  bf16_t* wff1T  = (bf16_t*)ws; ws += (size_t)4 * 8192 * 1024 * 2;  // 67 MB
  bf16_t* wff2T  = (bf16_t*)ws; ws += (size_t)4 * 1024 * 4096 * 2;  // 34 MB
  bf16_t* h_bf   = (bf16_t*)ws; ws += (size_t)MROWS * 1024 * 2;     //  4 MB
  bf16_t* qkv_bf = (bf16_t*)ws; ws += (size_t)MROWS * 3072 * 2;     // 13 MB
  bf16_t* o_bf   = (bf16_t*)ws; ws += (size_t)MROWS * 1024 * 2;     //  4 MB
  bf16_t* vT     = (bf16_t*)ws; ws += (size_t)32 * 64 * 1024 * 2;   //  4 MB
  bf16_t* ff_bf  = (bf16_t*)ws; ws += (size_t)MROWS * 4096 * 2;     // 17 MB
  if (ws_size < (size_t)(ws - (char*)d_ws)) return;  // visible fail

  hipMemcpyAsync(xout, x_in, (size_t)MROWS * DIM * 4,
                 hipMemcpyDeviceToDevice, stream);

  // all 4 layers' weight transposes in ONE launch
  transpose_all<<<dim3(16384, 4), 256, 0, stream>>>(
      wqkv, wout, wff1, wff2, wqkvT, woutT, wff1T, wff2T);

  for (int l = 0; l < 4; ++l) {
    const bf16_t* wqkvTl = wqkvT + (size_t)l * 3072 * 1024;
    const bf16_t* woutTl = woutT + (size_t)l * 1024 * 1024;
    const bf16_t* wff1Tl = wff1T + (size_t)l * 8192 * 1024;
    const bf16_t* wff2Tl = wff2T + (size_t)l * 1024 * 4096;

    // ---- attention
    ln_kernel<<<MROWS, 256, 0, stream>>>(xout, ln1w + l * 1024,
                                         ln1b + l * 1024, h_bf);
    // qkv GEMM; V columns go straight to vT (transposed) in the epilogue
    gemm_bt<128, 128, 2, 2, 4><<<dim3(24, 16, 1), 256, 0, stream>>>(
        h_bf, 0, 0, 1024, wqkvTl, 0, 0, 1024, qkv_bf, 0, 0, 3072, 1024, 1.f,
        nullptr, nullptr, vT);
    flash_attn<<<dim3(16, 32), 256, 0, stream>>>(qkv_bf, vT, o_bf);
    // x += (o @ w_out + b_out) * ls1 : split-K=2 (512 blocks, 2/CU)
    gemm_bt<64, 128, 1, 4, 5><<<dim3(8, 32, 2), 256, 0, stream>>>(
        o_bf, 0, 512, 1024, woutTl, 0, 512, 1024, xout, 0, 0, 1024, 512, 1.f,
        bout + l * 1024, ls1 + l * 1024, nullptr);

    // ---- feedforward (GEGLU fused into 256^2 8-phase ff1 GEMM)
    ln_kernel<<<MROWS, 256, 0, stream>>>(xout, ln2w + l * 1024,
                                         ln2b + l * 1024, h_bf);
    gemm256_ff1<<<dim3(32, 8), 512, 0, stream>>>(
        h_bf, wff1Tl, ff_bf, bff1 + l * 8192, 1024);
    // x += (ff @ w_ff2 + b_ff2) * ls2 : split-K=4 (1024 blocks, 4/CU)
    gemm_bt<64, 128, 1, 4, 5><<<dim3(8, 32, 4), 256, 0, stream>>>(
        ff_bf, 0, 1024, 4096, wff2Tl, 0, 1024, 4096, xout, 0, 0, 1024, 1024,
        1.f, bff2 + l * 1024, ls2 + l * 1024, nullptr);
  }
}

// Round 5
// 1107.169 us; speedup vs baseline: 1.1069x; 1.0013x over previous
//
#include <hip/hip_runtime.h>
#include <cstdint>
#include <cstddef>

// ---------------------------------------------------------------- types
typedef __bf16 bf16_t;
typedef __bf16 bf16x8 __attribute__((ext_vector_type(8)));
typedef __bf16 bf16x4 __attribute__((ext_vector_type(4)));
typedef float  f32x4  __attribute__((ext_vector_type(4)));

#define DEV __device__ __forceinline__

static constexpr int   BATCH = 2;
static constexpr int   NTOK  = 1024;
static constexpr int   DIM   = 1024;
static constexpr int   MROWS = BATCH * NTOK;      // 2048 token rows
static constexpr float SCALE = 0.125f;            // 64^-0.5

// ------------------------------------------------------- global->LDS DMA
DEV void load_lds16(const bf16_t* g, bf16_t* s) {
  __builtin_amdgcn_global_load_lds(
      (const __attribute__((address_space(1))) void*)g,
      (__attribute__((address_space(3))) void*)s, 16, 0, 0);
}

// ------------------------------------------------------------ reductions
DEV float wave_sum(float v) {
#pragma unroll
  for (int m = 1; m < 64; m <<= 1) v += __shfl_xor(v, m, 64);
  return v;
}
DEV float block_sum(float v, float* sb) {
  v = wave_sum(v);
  __syncthreads();
  if ((threadIdx.x & 63) == 0) sb[threadIdx.x >> 6] = v;
  __syncthreads();
  return sb[0] + sb[1] + sb[2] + sb[3];
}

// ------------------------------------------------------------------ GEMM
// C[M,N] = A[M,K] @ B[K,N], with B given transposed: BT[N][K] (row-major).
// Fragment layout (verified):
//   A frag:  A[m = lane&15][k = (lane>>4)*8 + j]   -> 8 contiguous bf16
//   B frag:  BT[n = lane&15][k = (lane>>4)*8 + j]  -> 8 contiguous bf16
//   C/D:     col = lane&15, row = (lane>>4)*4 + reg
// MODE 0: C(bf16) = alpha * acc
// MODE 1: C(bf16) = acc + bias[col]
// MODE 2: C(f32) += (acc + bias[col]) * ls[col]   (residual update in place)
// MODE 4: QKV epilogue. cols < 2048 (Q,K) -> C as bf16; cols >= 2048 (V)
//         -> vtp[z=b*16+h][d][tok] transposed store (feeds flash_attn).
// MODE 5: split-K residual. blockIdx.z = split; A/B offset via sA1/sB1 =
//         Ksplit; K = Ksplit. C(f32) atomicAdd (acc + (z==0)*bias)*ls.
template <int BM, int BN, int WR, int WC, int MODE>
__global__ __launch_bounds__(256) void gemm_bt(
    const bf16_t* __restrict__ A, long sA0, long sA1, int lda,
    const bf16_t* __restrict__ B, long sB0, long sB1, int ldb,
    void* __restrict__ Cv, long sC0, long sC1, int ldc,
    int K, float alpha, const float* __restrict__ bias,
    const float* __restrict__ ls, bf16_t* __restrict__ vtp) {
  constexpr int TM = BM / WR / 16;
  constexpr int TN = BN / WC / 16;
  __shared__ __attribute__((aligned(16))) bf16_t As[BM * 32];
  __shared__ __attribute__((aligned(16))) bf16_t Bs[BN * 32];

  const int tid  = threadIdx.x;
  const int lane = tid & 63, wave = tid >> 6;
  const int z  = blockIdx.z;
  const int zh = z >> 4, zl = z & 15;
  A += (size_t)zh * sA0 + (size_t)zl * sA1;
  B += (size_t)zh * sB0 + (size_t)zl * sB1;

  const int m0 = blockIdx.y * BM, n0 = blockIdx.x * BN;
  const int wm = (wave / WC) * (BM / WR);
  const int wn = (wave % WC) * (BN / WC);
  const int fm = lane & 15, quad = lane >> 4;

  f32x4 acc[TM][TN] = {};

  for (int k0 = 0; k0 < K; k0 += 32) {
#pragma unroll
    for (int c = tid; c < BM * 4; c += 256) {
      const int row = c >> 2, kc = (c & 3) << 3;
      load_lds16(A + (size_t)(m0 + row) * lda + k0 + kc, &As[c * 8]);
    }
#pragma unroll
    for (int c = tid; c < BN * 4; c += 256) {
      const int row = c >> 2, kc = (c & 3) << 3;
      load_lds16(B + (size_t)(n0 + row) * ldb + k0 + kc, &Bs[c * 8]);
    }
    __syncthreads();

    bf16x8 af[TM], bfr[TN];
#pragma unroll
    for (int i = 0; i < TM; ++i)
      af[i] = *(const bf16x8*)&As[(wm + i * 16 + fm) * 32 + quad * 8];
#pragma unroll
    for (int j = 0; j < TN; ++j)
      bfr[j] = *(const bf16x8*)&Bs[(wn + j * 16 + fm) * 32 + quad * 8];
#pragma unroll
    for (int i = 0; i < TM; ++i)
#pragma unroll
      for (int j = 0; j < TN; ++j)
        acc[i][j] = __builtin_amdgcn_mfma_f32_16x16x32_bf16(af[i], bfr[j],
                                                            acc[i][j], 0, 0, 0);
    __syncthreads();
  }

  const size_t coff = (size_t)zh * sC0 + (size_t)zl * sC1;
  if constexpr (MODE == 4) {
    bf16_t* C = (bf16_t*)Cv;
#pragma unroll
    for (int i = 0; i < TM; ++i) {
#pragma unroll
      for (int j = 0; j < TN; ++j) {
        const int col  = n0 + wn + j * 16 + fm;
        const int rowb = m0 + wm + i * 16 + quad * 4;
        if (col < 2048) {  // Q,K region: normal bf16 store
#pragma unroll
          for (int r = 0; r < 4; ++r)
            C[(size_t)(rowb + r) * ldc + col] = (bf16_t)acc[i][j][r];
        } else {           // V region: transposed store into vT[z][d][tok]
          const int hh = (col - 2048) >> 6, d = (col - 2048) & 63;
#pragma unroll
          for (int r = 0; r < 4; ++r) {
            const int row = rowb + r, bb = row >> 10, tok = row & 1023;
            vtp[((size_t)(bb * 16 + hh) * 64 + d) * 1024 + tok] =
                (bf16_t)acc[i][j][r];
          }
        }
      }
    }
  } else if constexpr (MODE == 5) {
    float* C = (float*)Cv;
#pragma unroll
    for (int i = 0; i < TM; ++i) {
#pragma unroll
      for (int j = 0; j < TN; ++j) {
        const int col  = n0 + wn + j * 16 + fm;
        const int rowb = m0 + wm + i * 16 + quad * 4;
        const float lsv = ls[col];
        const float bl  = (zl == 0) ? bias[col] * lsv : 0.f;
#pragma unroll
        for (int r = 0; r < 4; ++r) {
          const size_t idx = (size_t)(rowb + r) * ldc + col;
          atomicAdd(&C[idx], acc[i][j][r] * lsv + bl);
        }
      }
    }
  } else {
#pragma unroll
    for (int i = 0; i < TM; ++i) {
#pragma unroll
      for (int j = 0; j < TN; ++j) {
        const int col  = n0 + wn + j * 16 + fm;
        const int rowb = m0 + wm + i * 16 + quad * 4;
#pragma unroll
        for (int r = 0; r < 4; ++r) {
          const float  v   = acc[i][j][r];
          const size_t idx = coff + (size_t)(rowb + r) * ldc + col;
          if constexpr (MODE == 0) {
            ((bf16_t*)Cv)[idx] = (bf16_t)(v * alpha);
          } else if constexpr (MODE == 1) {
            ((bf16_t*)Cv)[idx] = (bf16_t)(v + bias[col]);
          } else {
            float* C = (float*)Cv;
            C[idx]   = C[idx] + (v + bias[col]) * ls[col];
          }
        }
      }
    }
  }
}

// ------------------------------------------- 256x256 8-phase GEMM (ff1)
// C[2048][4096] = GEGLU(A[2048][K] @ BT_perm[8192][K] + bias), K=1024.
// BT rows are the a/g 16-interleaved permutation (transpose_all s2), so
// per-wave col-frag pairs (2p, 2p+1) = (a, g) for the same ff column.
// Schedule: verified in R3 (counted vmcnt(6), raw barriers, setprio).
__global__ __launch_bounds__(512, 2) void gemm256_ff1(
    const bf16_t* __restrict__ A,    // [2048][K]  h_bf
    const bf16_t* __restrict__ B,    // [8192][K]  wff1T (permuted)
    bf16_t* __restrict__ C,          // [2048][4096] ff_bf
    const float* __restrict__ bias,  // [8192]
    int K) {
  __shared__ __attribute__((aligned(16))) bf16_t As[2][2][256 * 32];
  __shared__ __attribute__((aligned(16))) bf16_t Bs[2][2][256 * 32];

  const int tid = threadIdx.x, lane = tid & 63, wave = tid >> 6;
  const int wm2 = wave >> 2, wn4 = wave & 3;
  const int fm = lane & 15, quad = lane >> 4;
  const int m0 = blockIdx.y * 256, n0 = blockIdx.x * 256;
  const int NK = K >> 6;

  auto stage = [&](const bf16_t* g, int base, int kt, int kh, bf16_t* s) {
#pragma unroll
    for (int it = 0; it < 2; ++it) {
      const int c = it * 512 + tid, row = c >> 2, kc = (c & 3) << 3;
      load_lds16(g + (size_t)(base + row) * K + kt * 64 + kh * 32 + kc,
                 s + c * 8);
    }
  };

  f32x4 acc[8][4] = {};

  stage(A, m0, 0, 0, &As[0][0][0]);
  stage(B, n0, 0, 0, &Bs[0][0][0]);
  stage(A, m0, 0, 1, &As[0][1][0]);
  stage(B, n0, 0, 1, &Bs[0][1][0]);
  if (NK > 1) {
    stage(A, m0, 1, 0, &As[1][0][0]);
    stage(B, n0, 1, 0, &Bs[1][0][0]);
    stage(A, m0, 1, 1, &As[1][1][0]);
  }
  asm volatile("s_waitcnt vmcnt(6)" ::: "memory");  // tile0 fully landed
  __builtin_amdgcn_sched_barrier(0);
  __builtin_amdgcn_s_barrier();

  const int ar = wm2 * 128 + fm;
  const int br = wn4 * 64 + fm;
  const int qo = quad * 8;

  for (int kt = 0; kt < NK; ++kt) {
    const int cur = kt & 1;
    bf16x8 af[8], b0, b1;

    // phase 0: ks0 x {n0,n1}
#pragma unroll
    for (int m = 0; m < 8; ++m)
      af[m] = *(const bf16x8*)&As[cur][0][(ar + m * 16) * 32 + qo];
    b0 = *(const bf16x8*)&Bs[cur][0][br * 32 + qo];
    b1 = *(const bf16x8*)&Bs[cur][0][(br + 16) * 32 + qo];
    if (kt + 1 < NK) stage(B, n0, kt + 1, 1, &Bs[cur ^ 1][1][0]);
    __builtin_amdgcn_s_barrier();
    __builtin_amdgcn_s_setprio(1);
#pragma unroll
    for (int m = 0; m < 8; ++m) {
      acc[m][0] = __builtin_amdgcn_mfma_f32_16x16x32_bf16(af[m], b0,
                                                          acc[m][0], 0, 0, 0);
      acc[m][1] = __builtin_amdgcn_mfma_f32_16x16x32_bf16(af[m], b1,
                                                          acc[m][1], 0, 0, 0);
    }
    __builtin_amdgcn_s_setprio(0);
    __builtin_amdgcn_s_barrier();

    // phase 1: ks0 x {n2,n3}
    b0 = *(const bf16x8*)&Bs[cur][0][(br + 32) * 32 + qo];
    b1 = *(const bf16x8*)&Bs[cur][0][(br + 48) * 32 + qo];
    if (kt + 2 < NK) stage(A, m0, kt + 2, 0, &As[cur][0][0]);
    __builtin_amdgcn_s_barrier();
    __builtin_amdgcn_s_setprio(1);
#pragma unroll
    for (int m = 0; m < 8; ++m) {
      acc[m][2] = __builtin_amdgcn_mfma_f32_16x16x32_bf16(af[m], b0,
                                                          acc[m][2], 0, 0, 0);
      acc[m][3] = __builtin_amdgcn_mfma_f32_16x16x32_bf16(af[m], b1,
                                                          acc[m][3], 0, 0, 0);
    }
    __builtin_amdgcn_s_setprio(0);
    __builtin_amdgcn_s_barrier();

    // phase 2: ks1 x {n2,n3}
#pragma unroll
    for (int m = 0; m < 8; ++m)
      af[m] = *(const bf16x8*)&As[cur][1][(ar + m * 16) * 32 + qo];
    b0 = *(const bf16x8*)&Bs[cur][1][(br + 32) * 32 + qo];
    b1 = *(const bf16x8*)&Bs[cur][1][(br + 48) * 32 + qo];
    if (kt + 2 < NK) stage(B, n0, kt + 2, 0, &Bs[cur][0][0]);
    __builtin_amdgcn_s_barrier();
    __builtin_amdgcn_s_setprio(1);
#pragma unroll
    for (int m = 0; m < 8; ++m) {
      acc[m][2] = __builtin_amdgcn_mfma_f32_16x16x32_bf16(af[m], b0,
                                                          acc[m][2], 0, 0, 0);
      acc[m][3] = __builtin_amdgcn_mfma_f32_16x16x32_bf16(af[m], b1,
                                                          acc[m][3], 0, 0, 0);
    }
    __builtin_amdgcn_s_setprio(0);
    __builtin_amdgcn_s_barrier();

    // phase 3: ks1 x {n0,n1}
    b0 = *(const bf16x8*)&Bs[cur][1][br * 32 + qo];
    b1 = *(const bf16x8*)&Bs[cur][1][(br + 16) * 32 + qo];
    if (kt + 2 < NK) stage(A, m0, kt + 2, 1, &As[cur][1][0]);
    asm volatile("s_waitcnt vmcnt(6)" ::: "memory");  // tile kt+1 landed
    __builtin_amdgcn_sched_barrier(0);
    __builtin_amdgcn_s_barrier();
    __builtin_amdgcn_s_setprio(1);
#pragma unroll
    for (int m = 0; m < 8; ++m) {
      acc[m][0] = __builtin_amdgcn_mfma_f32_16x16x32_bf16(af[m], b0,
                                                          acc[m][0], 0, 0, 0);
      acc[m][1] = __builtin_amdgcn_mfma_f32_16x16x32_bf16(af[m], b1,
                                                          acc[m][1], 0, 0, 0);
    }
    __builtin_amdgcn_s_setprio(0);
    __builtin_amdgcn_s_barrier();
  }

  // GEGLU epilogue: pairs (acc[m][2p], acc[m][2p+1]) = (a, g)
#pragma unroll
  for (int m = 0; m < 8; ++m) {
    const int rowb = m0 + wm2 * 128 + m * 16 + quad * 4;
#pragma unroll
    for (int p = 0; p < 2; ++p) {
      const int   cf = ((n0 + wn4 * 64 + p * 32) >> 1) + fm;
      const float ba = bias[cf], bg = bias[4096 + cf];
#pragma unroll
      for (int r = 0; r < 4; ++r) {
        const float a  = acc[m][2 * p][r] + ba;
        const float g  = acc[m][2 * p + 1][r] + bg;
        const float ge = 0.5f * g * (1.f + erff(g * 0.70710678118654752f));
        C[(size_t)(rowb + r) * 4096 + cf] = (bf16_t)(a * ge);
      }
    }
  }
}

// --------------------------------------------------------- flash attention
// One block per (64-row Q tile, z = b*16+h). 4 waves, each owning 16 Q rows.
// KV tiles of 128 tokens. S never hits HBM.
__global__ __launch_bounds__(256) void flash_attn(
    const bf16_t* __restrict__ qkv,   // [2][1024][3072] (V region unused)
    const bf16_t* __restrict__ vT,    // [32][64][1024]
    bf16_t* __restrict__ o) {         // [2][1024][1024] col = h*64+d
  constexpr int NT = 128;
  __shared__ __attribute__((aligned(16))) bf16_t Qs[2 * 64 * 32];   // 8 KB
  __shared__ __attribute__((aligned(16))) bf16_t Ks[2 * NT * 32];   // 16 KB
  __shared__ __attribute__((aligned(16))) bf16_t Vs[4 * 64 * 32];   // 16 KB
  __shared__ __attribute__((aligned(16))) bf16_t Ps[4][4 * 16 * 32];// 16 KB

  const int tid = threadIdx.x, lane = tid & 63, wave = tid >> 6;
  const int fm = lane & 15, quad = lane >> 4;
  const int z = blockIdx.y, b = z >> 4, h = z & 15;
  const int q0 = blockIdx.x * 64;
  const bf16_t* qb  = qkv + (size_t)b * 1024 * 3072 + h * 64;
  const bf16_t* kb  = qb + 1024;
  const bf16_t* vtb = vT + (size_t)z * 64 * 1024;

  // stage Q tile: layout [kk(2)][row(64)][32]
  for (int c = tid; c < 512; c += 256) {
    const int kk = c >> 8, rr = (c >> 2) & 63, ii = c & 3;
    load_lds16(qb + (size_t)(q0 + rr) * 3072 + kk * 32 + ii * 8, &Qs[c * 8]);
  }
  __syncthreads();
  bf16x8 qf[2];
  qf[0] = *(const bf16x8*)&Qs[(wave * 16 + fm) * 32 + quad * 8];
  qf[1] = *(const bf16x8*)&Qs[64 * 32 + (wave * 16 + fm) * 32 + quad * 8];

  float mr[4], lr[4];
  f32x4 oacc[4];
#pragma unroll
  for (int r = 0; r < 4; ++r) { mr[r] = -1e30f; lr[r] = 0.f; }
#pragma unroll
  for (int t = 0; t < 4; ++t) oacc[t] = (f32x4){0.f, 0.f, 0.f, 0.f};

  for (int kv0 = 0; kv0 < 1024; kv0 += NT) {
    __syncthreads();  // all waves done reading previous K/V tiles
    // K tile [kk(2)][tok(128)][32]
    for (int c = tid; c < NT * 8; c += 256) {
      const int kk = c >> 9, rr = (c >> 2) & 127, ii = c & 3;
      load_lds16(kb + (size_t)(kv0 + rr) * 3072 + kk * 32 + ii * 8, &Ks[c * 8]);
    }
    // V^T tile [tc(4)][d(64)][32]
    for (int c = tid; c < 1024; c += 256) {
      const int tc = c >> 8, rr = (c >> 2) & 63, ii = c & 3;
      load_lds16(vtb + (size_t)rr * 1024 + kv0 + tc * 32 + ii * 8, &Vs[c * 8]);
    }
    __syncthreads();

    // S = Q @ K^T  (8 column tiles of 16)
    f32x4 sc[8];
#pragma unroll
    for (int nt = 0; nt < 8; ++nt) {
      sc[nt] = (f32x4){0.f, 0.f, 0.f, 0.f};
#pragma unroll
      for (int kk = 0; kk < 2; ++kk) {
        const bf16x8 kf =
            *(const bf16x8*)&Ks[kk * NT * 32 + (nt * 16 + fm) * 32 + quad * 8];
        sc[nt] = __builtin_amdgcn_mfma_f32_16x16x32_bf16(qf[kk], kf, sc[nt],
                                                         0, 0, 0);
      }
    }
    // online softmax over this tile (rows = quad*4+r, cols across 16 lanes)
    float tmax[4] = {-1e30f, -1e30f, -1e30f, -1e30f};
#pragma unroll
    for (int nt = 0; nt < 8; ++nt)
#pragma unroll
      for (int r = 0; r < 4; ++r) {
        sc[nt][r] *= SCALE;
        tmax[r] = fmaxf(tmax[r], sc[nt][r]);
      }
#pragma unroll
    for (int m = 1; m < 16; m <<= 1)
#pragma unroll
      for (int r = 0; r < 4; ++r)
        tmax[r] = fmaxf(tmax[r], __shfl_xor(tmax[r], m, 64));
    float alpha[4], mn[4], ps[4];
#pragma unroll
    for (int r = 0; r < 4; ++r) {
      mn[r]    = fmaxf(mr[r], tmax[r]);
      alpha[r] = __expf(mr[r] - mn[r]);
      mr[r]    = mn[r];
      ps[r]    = 0.f;
    }
    // P = exp(S - m); write to per-wave LDS in [kk(4)][m(16)][32] layout
#pragma unroll
    for (int nt = 0; nt < 8; ++nt) {
      const int tcol = nt * 16 + fm, kk = tcol >> 5, tw = tcol & 31;
#pragma unroll
      for (int r = 0; r < 4; ++r) {
        const float p = __expf(sc[nt][r] - mn[r]);
        ps[r] += p;
        Ps[wave][kk * 512 + (quad * 4 + r) * 32 + tw] = (bf16_t)p;
      }
    }
#pragma unroll
    for (int m = 1; m < 16; m <<= 1)
#pragma unroll
      for (int r = 0; r < 4; ++r) ps[r] += __shfl_xor(ps[r], m, 64);
#pragma unroll
    for (int r = 0; r < 4; ++r) lr[r] = lr[r] * alpha[r] + ps[r];
#pragma unroll
    for (int t = 0; t < 4; ++t)
#pragma unroll
      for (int r = 0; r < 4; ++r) oacc[t][r] *= alpha[r];
    // drain this wave's LDS writes of P before reading fragments
    __builtin_amdgcn_s_waitcnt(0xC07F);  // lgkmcnt(0), vm/exp unconstrained
    // O += P @ V
#pragma unroll
    for (int kk = 0; kk < 4; ++kk) {
      const bf16x8 af =
          *(const bf16x8*)&Ps[wave][kk * 512 + fm * 32 + quad * 8];
#pragma unroll
      for (int t = 0; t < 4; ++t) {
        const bf16x8 vf =
            *(const bf16x8*)&Vs[kk * 64 * 32 + (t * 16 + fm) * 32 + quad * 8];
        oacc[t] = __builtin_amdgcn_mfma_f32_16x16x32_bf16(af, vf, oacc[t],
                                                          0, 0, 0);
      }
    }
  }

  // epilogue: normalize and store (C layout)
  const size_t orow0 = (size_t)b * 1024 + q0 + wave * 16 + quad * 4;
#pragma unroll
  for (int t = 0; t < 4; ++t) {
    const int col = h * 64 + t * 16 + fm;
#pragma unroll
    for (int r = 0; r < 4; ++r)
      o[(orow0 + r) * 1024 + col] = (bf16_t)(oacc[t][r] / lr[r]);
  }
}

// --------------------------------- fused weight transpose+cast, ALL layers
// 64x64 tiles, float4 reads, bf16x8 (16 B) writes. grid (4096, 4).
// LDS float[64][65]: both phases measured-free 2-way bank aliasing.
//   read : thread (t>>4, (t&15)*4) float4, 4 row-passes of 16
//   write: n-row t>>3 (+32*s), k-span (t&7)*8 -> 8 threads x 16 B = 128 B/row
// Segments/layer (64x64 tiles): qkv 768 | wout 256 | wff1 2048 perm | wff2 1024
//   wff1 perm: a-col n(<4096) -> ((n>>4)<<5)+(n&15); g-col -> +16 variant
__global__ __launch_bounds__(256) void transpose_all(
    const float* __restrict__ wqkv, const float* __restrict__ wout,
    const float* __restrict__ wff1, const float* __restrict__ wff2,
    bf16_t* __restrict__ wqkvT, bf16_t* __restrict__ woutT,
    bf16_t* __restrict__ wff1T, bf16_t* __restrict__ wff2T) {
  __shared__ float t[64][65];
  const int l = blockIdx.y;
  int bx = blockIdx.x;
  const float* W;
  bf16_t*      WT;
  int N, K;
  bool perm = false;
  if (bx < 768) {
    W = wqkv + (size_t)l * 1024 * 3072;
    WT = wqkvT + (size_t)l * 3072 * 1024; K = 1024; N = 3072;
  } else if (bx < 1024) {
    bx -= 768;
    W = wout + (size_t)l * 1024 * 1024;
    WT = woutT + (size_t)l * 1024 * 1024; K = 1024; N = 1024;
  } else if (bx < 3072) {
    bx -= 1024;
    W = wff1 + (size_t)l * 1024 * 8192;
    WT = wff1T + (size_t)l * 8192 * 1024; K = 1024; N = 8192;
    perm = true;
  } else {
    bx -= 3072;
    W = wff2 + (size_t)l * 4096 * 1024;
    WT = wff2T + (size_t)l * 1024 * 4096; K = 4096; N = 1024;
  }
  const int nbx = N >> 6;
  const int n0 = (bx % nbx) * 64, k0 = (bx / nbx) * 64;
  const int tid = threadIdx.x;

  // read: 64 rows x 16 float4
  const int rr = tid >> 4, cc = (tid & 15) * 4;
#pragma unroll
  for (int s = 0; s < 4; ++s) {
    const float4 v =
        *(const float4*)&W[(size_t)(k0 + rr + 16 * s) * N + n0 + cc];
    t[rr + 16 * s][cc]     = v.x;
    t[rr + 16 * s][cc + 1] = v.y;
    t[rr + 16 * s][cc + 2] = v.z;
    t[rr + 16 * s][cc + 3] = v.w;
  }
  __syncthreads();

  // write: 64 n-rows, 8 threads/row x bf16x8
  const int wn = tid >> 3, wk = (tid & 7) * 8;
#pragma unroll
  for (int s = 0; s < 2; ++s) {
    const int n = n0 + wn + 32 * s;
    int r;
    if (perm)
      r = (n < 4096) ? (((n >> 4) << 5) + (n & 15))
                     : ((((n - 4096) >> 4) << 5) + 16 + (n & 15));
    else
      r = n;
    bf16x8 o;
#pragma unroll
    for (int j = 0; j < 8; ++j) o[j] = (bf16_t)t[wk + j][wn + 32 * s];
    *(bf16x8*)&WT[(size_t)r * K + k0 + wk] = o;
  }
}

// -------------------------------------------------------------- layernorm
__global__ __launch_bounds__(256) void ln_kernel(const float* __restrict__ x,
                                                 const float* __restrict__ w,
                                                 const float* __restrict__ b,
                                                 bf16_t* __restrict__ out) {
  __shared__ float sb[4];
  const int row = blockIdx.x, tid = threadIdx.x;
  const float4 v = ((const float4*)(x + (size_t)row * DIM))[tid];
  float s = v.x + v.y + v.z + v.w;
  s = block_sum(s, sb);
  const float mu = s * (1.f / DIM);
  const float dx = v.x - mu, dy = v.y - mu, dz = v.z - mu, dw = v.w - mu;
  float q = dx * dx + dy * dy + dz * dz + dw * dw;
  q = block_sum(q, sb);
  const float rstd = rsqrtf(q * (1.f / DIM) + 1e-5f);
  const float4 wv = ((const float4*)w)[tid];
  const float4 bv = ((const float4*)b)[tid];
  bf16x4 o;
  o[0] = (bf16_t)(dx * rstd * wv.x + bv.x);
  o[1] = (bf16_t)(dy * rstd * wv.y + bv.y);
  o[2] = (bf16_t)(dz * rstd * wv.z + bv.z);
  o[3] = (bf16_t)(dw * rstd * wv.w + bv.w);
  ((bf16x4*)(out + (size_t)row * DIM))[tid] = o;
}

// ------------------------------------------------------------------ launch
extern "C" void kernel_launch(void* const* d_in, const int* in_sizes, int n_in,
                              void* d_out, int out_size, void* d_ws,
                              size_t ws_size, hipStream_t stream) {
  const float* x_in = (const float*)d_in[0];
  const float* ln1w = (const float*)d_in[1];
  const float* ln1b = (const float*)d_in[2];
  const float* wqkv = (const float*)d_in[3];
  const float* wout = (const float*)d_in[4];
  const float* bout = (const float*)d_in[5];
  const float* ls1  = (const float*)d_in[6];
  const float* ln2w = (const float*)d_in[7];
  const float* ln2b = (const float*)d_in[8];
  const float* wff1 = (const float*)d_in[9];
  const float* bff1 = (const float*)d_in[10];
  const float* wff2 = (const float*)d_in[11];
  const float* bff2 = (const float*)d_in[12];
  const float* ls2  = (const float*)d_in[13];
  float*       xout = (float*)d_out;

  // -------- workspace carve-up (~176 MB; all 4 layers' weights resident)
  char*   ws     = (char*)d_ws;
  bf16_t* wqkvT  = (bf16_t*)ws; ws += (size_t)4 * 3072 * 1024 * 2;  // 25 MB
  bf16_t* woutT  = (bf16_t*)ws; ws += (size_t)4 * 1024 * 1024 * 2;  //  8 MB
  bf16_t* wff1T  = (bf16_t*)ws; ws += (size_t)4 * 8192 * 1024 * 2;  // 67 MB
  bf16_t* wff2T  = (bf16_t*)ws; ws += (size_t)4 * 1024 * 4096 * 2;  // 34 MB
  bf16_t* h_bf   = (bf16_t*)ws; ws += (size_t)MROWS * 1024 * 2;     //  4 MB
  bf16_t* qkv_bf = (bf16_t*)ws; ws += (size_t)MROWS * 3072 * 2;     // 13 MB
  bf16_t* o_bf   = (bf16_t*)ws; ws += (size_t)MROWS * 1024 * 2;     //  4 MB
  bf16_t* vT     = (bf16_t*)ws; ws += (size_t)32 * 64 * 1024 * 2;   //  4 MB
  bf16_t* ff_bf  = (bf16_t*)ws; ws += (size_t)MROWS * 4096 * 2;     // 17 MB
  if (ws_size < (size_t)(ws - (char*)d_ws)) return;  // visible fail

  hipMemcpyAsync(xout, x_in, (size_t)MROWS * DIM * 4,
                 hipMemcpyDeviceToDevice, stream);

  // all 4 layers' weight transposes in ONE launch (64x64 vectorized tiles)
  transpose_all<<<dim3(4096, 4), 256, 0, stream>>>(
      wqkv, wout, wff1, wff2, wqkvT, woutT, wff1T, wff2T);

  for (int l = 0; l < 4; ++l) {
    const bf16_t* wqkvTl = wqkvT + (size_t)l * 3072 * 1024;
    const bf16_t* woutTl = woutT + (size_t)l * 1024 * 1024;
    const bf16_t* wff1Tl = wff1T + (size_t)l * 8192 * 1024;
    const bf16_t* wff2Tl = wff2T + (size_t)l * 1024 * 4096;

    // ---- attention
    ln_kernel<<<MROWS, 256, 0, stream>>>(xout, ln1w + l * 1024,
                                         ln1b + l * 1024, h_bf);
    // qkv GEMM; V columns go straight to vT (transposed) in the epilogue
    gemm_bt<128, 128, 2, 2, 4><<<dim3(24, 16, 1), 256, 0, stream>>>(
        h_bf, 0, 0, 1024, wqkvTl, 0, 0, 1024, qkv_bf, 0, 0, 3072, 1024, 1.f,
        nullptr, nullptr, vT);
    flash_attn<<<dim3(16, 32), 256, 0, stream>>>(qkv_bf, vT, o_bf);
    // x += (o @ w_out + b_out) * ls1 : split-K=2 (512 blocks, 2/CU)
    gemm_bt<64, 128, 1, 4, 5><<<dim3(8, 32, 2), 256, 0, stream>>>(
        o_bf, 0, 512, 1024, woutTl, 0, 512, 1024, xout, 0, 0, 1024, 512, 1.f,
        bout + l * 1024, ls1 + l * 1024, nullptr);

    // ---- feedforward (GEGLU fused into 256^2 8-phase ff1 GEMM)
    ln_kernel<<<MROWS, 256, 0, stream>>>(xout, ln2w + l * 1024,
                                         ln2b + l * 1024, h_bf);
    gemm256_ff1<<<dim3(32, 8), 512, 0, stream>>>(
        h_bf, wff1Tl, ff_bf, bff1 + l * 8192, 1024);
    // x += (ff @ w_ff2 + b_ff2) * ls2 : split-K=4 (1024 blocks, 4/CU)
    gemm_bt<64, 128, 1, 4, 5><<<dim3(8, 32, 4), 256, 0, stream>>>(
        ff_bf, 0, 1024, 4096, wff2Tl, 0, 1024, 4096, xout, 0, 0, 1024, 1024,
        1.f, bff2 + l * 1024, ls2 + l * 1024, nullptr);
  }
}